// Round 16
// baseline (167.003 us; speedup 1.0000x reference)
//
#include <hip/hip_runtime.h>
#include <hip/hip_bf16.h>

typedef unsigned short u16;
typedef unsigned int u32;
typedef __attribute__((ext_vector_type(4))) float f32x4;
typedef float f32x4u __attribute__((ext_vector_type(4), aligned(4)));
typedef __attribute__((ext_vector_type(8))) short bf16x8;

__device__ __forceinline__ u16 f2bf(float f) {
    union { float f; u32 u; } v; v.f = f;
    return (u16)((v.u + 0x7FFFu + ((v.u >> 16) & 1u)) >> 16);
}
__device__ __forceinline__ float bf2f(u16 b) {
    union { u32 u; float f; } v; v.u = ((u32)b) << 16;
    return v.f;
}
__device__ __forceinline__ void st_out(float* p, float v) { *p = v; }
__device__ __forceinline__ void st_out(u16* p, float v) { *p = f2bf(v); }

__device__ __forceinline__ f32x4 mfma16(bf16x8 a, bf16x8 b, f32x4 c) {
    return __builtin_amdgcn_mfma_f32_16x16x32_bf16(a, b, c, 0, 0, 0);
}
__device__ __forceinline__ u32 cvt_pk_bf16(float lo, float hi) {
    u32 r;
    asm("v_cvt_pk_bf16_f32 %0, %1, %2" : "=v"(r) : "v"(lo), "v"(hi));
    return r;
}

#define GLD_LDS16(g, l) __builtin_amdgcn_global_load_lds( \
    (const __attribute__((address_space(1))) void*)(g),   \
    (__attribute__((address_space(3))) void*)(l), 16, 0, 0)

#define LOG2E 1.4426950408889634f
#define QSCALE 0.12751743f   /* (1/sqrt(128)) * log2e */

// ---------------- K_prep: tables + W transposes + x convert (fused) ----------------
__global__ __launch_bounds__(256) void k_prep(
    const float* __restrict__ W_attn, const float* __restrict__ W_proj,
    const float* __restrict__ x, const float* __restrict__ decay_raw,
    u16* __restrict__ WaT, u16* __restrict__ WpT, u16* __restrict__ Xb,
    float* __restrict__ bias_tab, float* __restrict__ cosT, float* __restrict__ sinT) {
    __shared__ float tile[64][65];
    const int b = blockIdx.x, tid = threadIdx.x;
    if (b < 4096) {
        // transpose f32 (R x Cc) -> bf16 (Cc x R)
        const float* src; u16* dst; int R, Cc, bx, by;
        if (b < 3072) { src = W_attn; dst = WaT; R = 2048; Cc = 6144; bx = b % 96; by = b / 96; }
        else          { src = W_proj; dst = WpT; R = 2048; Cc = 2048; bx = (b - 3072) & 31; by = (b - 3072) >> 5; }
        int c0 = bx * 64, r0 = by * 64;
#pragma unroll
        for (int it = 0; it < 16; ++it) {
            int idx = it * 256 + tid;
            int r = idx >> 6, c = idx & 63;
            tile[r][c] = src[(size_t)(r0 + r) * Cc + c0 + c];
        }
        __syncthreads();
        // vectorized write: each thread packs 4 consecutive rr into uint2 (8B/lane)
#pragma unroll
        for (int it = 0; it < 4; ++it) {
            int idx = it * 256 + tid;              // 0..1023
            int cc = idx >> 4;                     // 0..63
            int rr0 = (idx & 15) * 4;
            u32 lo = (u32)f2bf(tile[rr0][cc])     | ((u32)f2bf(tile[rr0 + 1][cc]) << 16);
            u32 hi = (u32)f2bf(tile[rr0 + 2][cc]) | ((u32)f2bf(tile[rr0 + 3][cc]) << 16);
            uint2 p; p.x = lo; p.y = hi;
            *(uint2*)(dst + (size_t)(c0 + cc) * R + r0 + rr0) = p;
        }
    } else if (b < 6144) {
        int i = (b - 4096) * 256 + tid;          // 524288 float4s
        float4 v = ((const float4*)x)[i];
        u32 p0 = (u32)f2bf(v.x) | ((u32)f2bf(v.y) << 16);
        u32 p1 = (u32)f2bf(v.z) | ((u32)f2bf(v.w) << 16);
        uint2 p; p.x = p0; p.y = p1;
        *(uint2*)(Xb + (size_t)i * 4) = p;
    } else {
        int i = (b - 6144) * 256 + tid;
        if (i < 16 * 2048) {
            int h = i >> 11, dist = i & 2047;
            float dec = log1pf(expf(decay_raw[h]));
            bias_tab[i] = -log1pf(dec * log1pf((float)dist)) * LOG2E;   // log2 units
        }
        if (i < 1024 * 64) {
            int t = i >> 6, j = i & 63;
            float inv = expf(-logf(10000.0f) * (float)j / 64.0f);
            float ang = (float)(1024 + t) * inv;
            cosT[i] = cosf(ang);
            sinT[i] = sinf(ang);
        }
    }
}

// ---------------- GEMM: A (MxK) bf16 row-major, Bt (NxK) bf16 row-major ----------------
// Double-buffered 2-phase, ONE __syncthreads per tile (R4/R8/R14-proven stable).
// 1D grid with XCD-chunked swizzle: each XCD gets a contiguous N-slice (all M)
// so its B panel is L2-resident. Requires gridDim.x % 8 == 0.
template<int BM, int BN, int WRG, int WCG, typename OT>
__global__ __launch_bounds__(256) void k_gemm_bt(
    const u16* __restrict__ A, const u16* __restrict__ Bt,
    const float* __restrict__ bias, OT* __restrict__ C,
    int M, int N, int K) {
    constexpr int BK = 64;
    constexpr int WM = BM / WRG;
    constexpr int WN = BN / WCG;
    constexpr int MR = WM / 16;
    constexpr int NR = WN / 16;
    constexpr int LDSZ = (BM + BN) * BK * 2;
    __shared__ char lds[2][LDSZ];

    const int tid = threadIdx.x;
    const int lane = tid & 63, wid = tid >> 6;
    const int wr = wid / WCG, wc = wid % WCG;
    const int lhi = lane >> 4, llo = lane & 15;

    // XCD-chunked swizzle: xcd = bid % 8 gets work ids [xcd*per, (xcd+1)*per)
    const int per = gridDim.x >> 3;
    const int w = (blockIdx.x & 7) * per + (blockIdx.x >> 3);
    const int mblocks = M / BM;
    const int m0 = (w % mblocks) * BM, n0 = (w / mblocks) * BN;   // n-major chunks

    f32x4 acc[MR][NR];
#pragma unroll
    for (int m = 0; m < MR; ++m)
#pragma unroll
        for (int n = 0; n < NR; ++n)
            acc[m][n] = f32x4{0.f, 0.f, 0.f, 0.f};

    auto stage = [&](int buf, int k0) {
        char* ldsA = &lds[buf][0];
        char* ldsB = &lds[buf][0] + BM * BK * 2;
#pragma unroll
        for (int it = 0; it < (BM * 8) / 256; ++it) {
            int ci = it * 256 + wid * 64 + lane;
            int r = ci >> 3, c = ci & 7;
            int sc = c ^ (r & 7);
            GLD_LDS16(A + (size_t)(m0 + r) * K + k0 + sc * 8,
                      ldsA + (it * 256 + wid * 64) * 16);
        }
#pragma unroll
        for (int it = 0; it < (BN * 8) / 256; ++it) {
            int ci = it * 256 + wid * 64 + lane;
            int r = ci >> 3, c = ci & 7;
            int sc = c ^ (r & 7);
            GLD_LDS16(Bt + (size_t)(n0 + r) * K + k0 + sc * 8,
                      ldsB + (it * 256 + wid * 64) * 16);
        }
    };

    stage(0, 0);
    __syncthreads();
    int cur = 0;
    for (int k0 = 0; k0 < K; k0 += BK) {
        if (k0 + BK < K) stage(cur ^ 1, k0 + BK);
        const char* ldsA = &lds[cur][0];
        const char* ldsB = &lds[cur][0] + BM * BK * 2;
#pragma unroll
        for (int kk = 0; kk < BK; kk += 32) {
            bf16x8 af[MR], bfr[NR];
            const int clb = (kk >> 3) + lhi;
#pragma unroll
            for (int m = 0; m < MR; ++m) {
                int row = wr * WM + m * 16 + llo;
                af[m] = *(const bf16x8*)(ldsA + row * 128 + ((clb ^ (row & 7)) << 4));
            }
#pragma unroll
            for (int n = 0; n < NR; ++n) {
                int row = wc * WN + n * 16 + llo;
                bfr[n] = *(const bf16x8*)(ldsB + row * 128 + ((clb ^ (row & 7)) << 4));
            }
#pragma unroll
            for (int m = 0; m < MR; ++m)
#pragma unroll
                for (int n = 0; n < NR; ++n)
                    acc[m][n] = mfma16(af[m], bfr[n], acc[m][n]);
        }
        __syncthreads();
        cur ^= 1;
    }
#pragma unroll
    for (int m = 0; m < MR; ++m) {
        int row = m0 + wr * WM + m * 16 + lhi * 4;
#pragma unroll
        for (int n = 0; n < NR; ++n) {
            int col = n0 + wc * WN + n * 16 + llo;
            float bv = bias[col];
#pragma unroll
            for (int j = 0; j < 4; ++j)
                st_out(&C[(size_t)(row + j) * N + col], acc[m][n][j] + bv);
        }
    }
}

// ---------------- K_mid: RoPE q/k + cached K copy + V assemble (fused) ----------------
__global__ __launch_bounds__(256) void k_mid(
    const u16* __restrict__ qkv,
    const float* __restrict__ cosT, const float* __restrict__ sinT,
    const float* __restrict__ cached_k, const float* __restrict__ cached_v,
    u16* __restrict__ qb, u16* __restrict__ kb,
    float* __restrict__ out_k, float* __restrict__ out_v, u16* __restrict__ vt) {
    __shared__ u16 tile[64][65];
    const int b = blockIdx.x;
    if (b < 4096) {
        int i = b * 256 + threadIdx.x;             // 16*1024*64
        int j = i & 63;
        int t = (i >> 6) & 1023;
        int h = i >> 16;
        const u16* row = qkv + (size_t)t * 6144;
        float q1 = bf2f(row[h * 128 + j]),        q2 = bf2f(row[h * 128 + j + 64]);
        float k1 = bf2f(row[2048 + h * 128 + j]), k2 = bf2f(row[2048 + h * 128 + j + 64]);
        float cv = cosT[t * 64 + j], sv = sinT[t * 64 + j];
        float qo1 = q1 * cv - q2 * sv, qo2 = q1 * sv + q2 * cv;
        float ko1 = k1 * cv - k2 * sv, ko2 = k1 * sv + k2 * cv;
        size_t qoff = ((size_t)h * 1024 + t) * 128 + j;
        qb[qoff] = f2bf(qo1 * QSCALE); qb[qoff + 64] = f2bf(qo2 * QSCALE);
        size_t koff = ((size_t)h * 2048 + 1024 + t) * 128 + j;
        kb[koff] = f2bf(ko1); kb[koff + 64] = f2bf(ko2);
        out_k[koff] = ko1; out_k[koff + 64] = ko2;
    } else if (b < 12288) {
        int i = (b - 4096) * 256 + threadIdx.x;    // 16*1024*128
        int d = i & 127, s = (i >> 7) & 1023, h = i >> 17;
        float v = cached_k[i];
        size_t off = ((size_t)h * 2048 + s) * 128 + d;
        out_k[off] = v;
        kb[off] = f2bf(v);
    } else {
        // V assemble: out_v f32 + per-head transposed bf16
        int idx2 = b - 12288;                      // 1024 blocks
        int s0 = (idx2 & 31) * 64, d0 = ((idx2 >> 5) & 1) * 64, h = idx2 >> 6;
        int tid = threadIdx.x;
#pragma unroll
        for (int it = 0; it < 16; ++it) {
            int idx = it * 256 + tid;
            int r = idx >> 6, c = idx & 63;
            int s = s0 + r, d = d0 + c;
            u16 v = (s < 1024)
                ? f2bf(cached_v[((size_t)h * 1024 + s) * 128 + d])
                : qkv[(size_t)(s - 1024) * 6144 + 4096 + h * 128 + d];
            tile[r][c] = v;
            out_v[((size_t)h * 2048 + s) * 128 + d] = bf2f(v);
        }
        __syncthreads();
        // vectorized transpose write: 4 consecutive ss per thread -> uint2
#pragma unroll
        for (int it = 0; it < 4; ++it) {
            int idx = it * 256 + tid;              // 0..1023
            int dd = idx >> 4;                     // 0..63
            int ss0 = (idx & 15) * 4;
            u32 lo = (u32)tile[ss0][dd]     | ((u32)tile[ss0 + 1][dd] << 16);
            u32 hi = (u32)tile[ss0 + 2][dd] | ((u32)tile[ss0 + 3][dd] << 16);
            uint2 p; p.x = lo; p.y = hi;
            *(uint2*)(vt + ((size_t)h * 128 + d0 + dd) * 2048 + s0 + ss0) = p;
        }
    }
}

// ---------------- K4: flash attention v7 (V-direct, issue-order-fixed) ----------------
// 4 waves x 16 q-rows, 4-way split-S (grid 1024 = 4 blocks/CU), qt-descending,
// KVBLK=32, K double-buffered in LDS; V + bias loaded direct from global (L2)
// in OLDEST-FIRST issue order [bias -> V -> K-stage] so consumption order
// [bias(vmcnt 10) -> V(vmcnt 2) -> barrier] never drains the K prefetch mid-tile.
// Sync structure identical to R14 (proven stable). Numerics = R15 (absmax 0.031).
__global__ __launch_bounds__(256, 4) void k_attn(
    const u16* __restrict__ qb,   // [16][1024][128], pre-scaled
    const u16* __restrict__ kb,   // [16][2048][128]
    const u16* __restrict__ vt,   // [16][128][2048]
    const float* __restrict__ bias_tab, // [16][2048], log2 units
    u16* __restrict__ Pacc,       // [1024 slots][64][128] bf16
    float* __restrict__ Pm,       // [1024 slots][64]
    float* __restrict__ Pl) {     // [1024 slots][64]
    __shared__ char ldsK[2][32 * 256];   // 8 KB each

    const int bid = blockIdx.x;
    const int xcd = bid & 7, idx = bid >> 3;
    const int work = xcd * 128 + idx;              // 2 heads per XCD
    const int h = work >> 6, rem = work & 63;
    const int qt = 15 - (rem >> 2), chunk = rem & 3;   // qt descending: big first
    const int qbase = qt * 64;
    const int tid = threadIdx.x, lane = tid & 63, wid = tid >> 6;
    const int lhi = lane >> 4, llo = lane & 15;
    const int slot = (h * 16 + qt) * 4 + chunk;

    const u16* kg = kb + (size_t)h * 2048 * 128;
    const u16* vg = vt + (size_t)h * 128 * 2048;
    const float* bt = bias_tab + h * 2048;

    // Q as B-operand fragment: col (n) = llo = q, k-chunks per lhi
    bf16x8 qf[4];
    {
        const u16* qrow = qb + ((size_t)h * 1024 + qbase + wid * 16 + llo) * 128;
#pragma unroll
        for (int c = 0; c < 4; ++c)
            qf[c] = *(const bf16x8*)(qrow + c * 32 + lhi * 8);
    }

    f32x4 acc[8];
#pragma unroll
    for (int d = 0; d < 8; ++d) acc[d] = f32x4{0.f, 0.f, 0.f, 0.f};
    float mrow = -3e38f;      // running max for q = llo (uniform across lhi groups)
    float lrow = 0.f;         // per-lane partial sum (reduced across lhi at end)

    const int ntiles = 34 + 2 * qt;                // 32-key tiles
    const int qpos = 1024 + qbase + wid * 16 + llo;

    auto stage = [&](int b, int st) {
        int sbase = st * 32;
#pragma unroll
        for (int it = 0; it < 2; ++it) {           // K: 32 rows x 16 chunks of 16B
            int ci = it * 256 + tid;
            int r = ci >> 4, c = ci & 15;
            int sc = c ^ (r & 7);
            GLD_LDS16(kg + (size_t)(sbase + r) * 128 + sc * 8,
                      &ldsK[b][0] + (it * 256 + wid * 64) * 16);
        }
    };

    // in-register P permutation: p0..p3 hold keys {lhi*4+0,1},{2,3},{16+lhi*4+0,1},{2,3}
    // for q=llo -> A-fragment (row=q=llo, keys lhi*8..lhi*8+7) via xor16/32/48 exchanges
    auto permP = [&](u32 p0, u32 p1, u32 p2, u32 p3) -> bf16x8 {
        u32 r16a = (u32)__shfl_xor((int)(lhi == 1 ? p0 : p2), 16);
        u32 r16b = (u32)__shfl_xor((int)(lhi == 1 ? p1 : p3), 16);
        u32 r32a = (u32)__shfl_xor((int)(lhi == 3 ? p0 : p2), 32);
        u32 r32b = (u32)__shfl_xor((int)(lhi == 3 ? p1 : p3), 32);
        u32 r48a = (u32)__shfl_xor((int)(lhi == 2 ? p0 : p2), 48);
        u32 r48b = (u32)__shfl_xor((int)(lhi == 2 ? p1 : p3), 48);
        union { u32 w[4]; bf16x8 v; } u;
        u.w[0] = lhi == 0 ? p0 : lhi == 1 ? r48a : lhi == 2 ? r32a : r16a;
        u.w[1] = lhi == 0 ? p1 : lhi == 1 ? r48b : lhi == 2 ? r32b : r16b;
        u.w[2] = lhi == 0 ? r16a : lhi == 1 ? r32a : lhi == 2 ? r48a : p2;
        u.w[3] = lhi == 0 ? r16b : lhi == 1 ? r32b : lhi == 2 ? r48b : p3;
        return u.v;
    };

    // descending tile order: near-diagonal (high-bias) first -> few rescales
    const int st0 = chunk + 4 * ((ntiles - 1 - chunk) >> 2);
    stage(0, st0);
    __syncthreads();
    int cur = 0;
    for (int st = st0; st >= chunk; st -= 4) {
        const int sbase = st * 32;
        const char* lK = &ldsK[cur][0];

        // ---- issue group 1 (oldest): bias windows ----
        const int D0 = qpos - sbase - lhi * 4;
        f32x4u wB = *(const f32x4u*)(bt + (D0 - 3 < 0 ? 0 : D0 - 3));
        f32x4u wC = *(const f32x4u*)(bt + (D0 - 19 < 0 ? 0 : D0 - 19));
        __builtin_amdgcn_sched_barrier(0);

        // ---- issue group 2: V fragments direct from global (L2-resident) ----
        bf16x8 vfr[8];
#pragma unroll
        for (int db = 0; db < 8; ++db) {
            int dr = db * 16 + llo;
            vfr[db] = *(const bf16x8*)(vg + (size_t)dr * 2048 + sbase + lhi * 8);
        }
        __builtin_amdgcn_sched_barrier(0);

        // ---- issue group 3 (newest): K stage for next tile ----
        if (st >= chunk + 4) stage(cur ^ 1, st - 4);

        // swapped QK^T: A = K rows (keys), B = Q (q = llo)
        f32x4 sc4[2];
        __builtin_amdgcn_s_setprio(1);
#pragma unroll
        for (int sub = 0; sub < 2; ++sub) {
            f32x4 s4 = f32x4{0.f, 0.f, 0.f, 0.f};
            int key = sub * 16 + llo;
#pragma unroll
            for (int c2 = 0; c2 < 4; ++c2) {
                int cl = c2 * 4 + lhi;
                bf16x8 kf = *(const bf16x8*)(lK + key * 256 + ((cl ^ (key & 7)) << 4));
                s4 = mfma16(kf, qf[c2], s4);
            }
            sc4[sub] = s4;
        }
        __builtin_amdgcn_s_setprio(0);

        // bias + causal mask (wave-uniform branch; only diagonal tiles mask)
        if (sbase + 31 <= 1024 + qbase + wid * 16) {
#pragma unroll
            for (int j = 0; j < 4; ++j) {
                sc4[0][j] += wB[3 - j];
                sc4[1][j] += wC[3 - j];
            }
        } else {
#pragma unroll
            for (int sub = 0; sub < 2; ++sub)
#pragma unroll
                for (int j = 0; j < 4; ++j) {
                    int key = sbase + sub * 16 + lhi * 4 + j;
                    int dist = qpos - key;
                    float bv = bt[dist < 0 ? 0 : dist];
                    sc4[sub][j] = (dist < 0) ? -3e38f : sc4[sub][j] + bv;
                }
        }

        // defer-max (base-2): lane-local max over 8 keys; rescale past threshold only
        float tmax = fmaxf(fmaxf(fmaxf(sc4[0][0], sc4[0][1]), fmaxf(sc4[0][2], sc4[0][3])),
                           fmaxf(fmaxf(sc4[1][0], sc4[1][1]), fmaxf(sc4[1][2], sc4[1][3])));
        int ok = (tmax <= mrow + 8.0f) ? 1 : 0;
        if (!__all(ok)) {
            float t = tmax;
            t = fmaxf(t, __shfl_xor(t, 16));
            t = fmaxf(t, __shfl_xor(t, 32));
            float mnew = fmaxf(mrow, t);
            float fs = exp2f(mrow - mnew);
            mrow = mnew;
            lrow *= fs;
            float fsj[4];
#pragma unroll
            for (int j = 0; j < 4; ++j)
                fsj[j] = __shfl(fs, lhi * 4 + j);   // acc rows: q = lhi*4+j
#pragma unroll
            for (int d = 0; d < 8; ++d)
#pragma unroll
                for (int j = 0; j < 4; ++j) acc[d][j] *= fsj[j];
        }

        // P = 2^(s-m) in-register; pack to bf16; lrow sums the PACKED values
        float p[8];
#pragma unroll
        for (int sub = 0; sub < 2; ++sub)
#pragma unroll
            for (int j = 0; j < 4; ++j)
                p[sub * 4 + j] = exp2f(sc4[sub][j] - mrow);
        u32 pk0 = cvt_pk_bf16(p[0], p[1]), pk1 = cvt_pk_bf16(p[2], p[3]);
        u32 pk2 = cvt_pk_bf16(p[4], p[5]), pk3 = cvt_pk_bf16(p[6], p[7]);
        lrow += bf2f((u16)(pk0 & 0xFFFF)) + bf2f((u16)(pk0 >> 16))
              + bf2f((u16)(pk1 & 0xFFFF)) + bf2f((u16)(pk1 >> 16))
              + bf2f((u16)(pk2 & 0xFFFF)) + bf2f((u16)(pk2 >> 16))
              + bf2f((u16)(pk3 & 0xFFFF)) + bf2f((u16)(pk3 >> 16));
        bf16x8 pa = permP(pk0, pk1, pk2, pk3);

        // PV: A = P (rows = q), B = V fragments (in registers; loads are older
        // than the K-stage ops so the wait here leaves the K prefetch in flight)
        __builtin_amdgcn_s_setprio(1);
#pragma unroll
        for (int db = 0; db < 8; ++db)
            acc[db] = mfma16(pa, vfr[db], acc[db]);
        __builtin_amdgcn_s_setprio(0);
        __syncthreads();
        cur ^= 1;
    }

    // final sum-reduce of per-lane lrow partials across lhi groups
    {
        float t = lrow;
        t += __shfl_xor(t, 16);
        t += __shfl_xor(t, 32);
        lrow = t;
    }

    if (lhi == 0) {
        int r = wid * 16 + llo;
        Pm[(size_t)slot * 64 + r] = mrow;
        Pl[(size_t)slot * 64 + r] = lrow;
    }
#pragma unroll
    for (int db = 0; db < 8; ++db)
#pragma unroll
        for (int j = 0; j < 4; ++j) {
            int r = wid * 16 + lhi * 4 + j;        // q row
            Pacc[(size_t)slot * 8192 + r * 128 + db * 16 + llo] = f2bf(acc[db][j]);
        }
}

// ---------------- K4b: merge 4-way split-S partials (1024 blocks, 4/CU) ----------------
__global__ __launch_bounds__(256) void k_merge(
    const u16* __restrict__ Pacc, const float* __restrict__ Pm,
    const float* __restrict__ Pl, u16* __restrict__ yb) {
    const int b = blockIdx.x;
    const int h = b >> 6, qt = (b >> 2) & 15, quarter = b & 3;
    const int slot0 = (h * 16 + qt) * 4;
    const int tid = threadIdx.x;
    const int r = tid >> 2, dd = (tid & 3) * 8 + quarter * 32;

    float m[4], l[4];
#pragma unroll
    for (int c = 0; c < 4; ++c) {
        m[c] = Pm[(size_t)(slot0 + c) * 64 + r];
        l[c] = Pl[(size_t)(slot0 + c) * 64 + r];
    }
    float M = fmaxf(fmaxf(m[0], m[1]), fmaxf(m[2], m[3]));
    float w[4], L = 0.f;
#pragma unroll
    for (int c = 0; c < 4; ++c) {
        w[c] = exp2f(m[c] - M);
        L += w[c] * l[c];
    }
    float inv = 1.0f / L;

    float y[8];
#pragma unroll
    for (int i = 0; i < 8; ++i) y[i] = 0.f;
#pragma unroll
    for (int c = 0; c < 4; ++c) {
        const uint4* pa = (const uint4*)(Pacc + (size_t)(slot0 + c) * 8192 + r * 128 + dd);
        float wc = w[c];
        uint4 v = *pa;
        u32 a[4] = {v.x, v.y, v.z, v.w};
#pragma unroll
        for (int p = 0; p < 4; ++p) {
            y[p * 2]     += wc * bf2f((u16)(a[p] & 0xFFFF));
            y[p * 2 + 1] += wc * bf2f((u16)(a[p] >> 16));
        }
    }
    int trow = qt * 64 + r;
    uint4 outv;
    u32* ow = (u32*)&outv;
#pragma unroll
    for (int k = 0; k < 4; ++k)
        ow[k] = (u32)f2bf(y[2 * k] * inv) | ((u32)f2bf(y[2 * k + 1] * inv) << 16);
    *(uint4*)(yb + (size_t)trow * 2048 + h * 128 + dd) = outv;
}

// ---------------- launch ----------------
extern "C" void kernel_launch(void* const* d_in, const int* in_sizes, int n_in,
                              void* d_out, int out_size, void* d_ws, size_t ws_size,
                              hipStream_t stream) {
    (void)in_sizes; (void)n_in; (void)out_size;
    const float* x         = (const float*)d_in[0];
    const float* cached_k  = (const float*)d_in[1];
    const float* cached_v  = (const float*)d_in[2];
    const float* W_attn    = (const float*)d_in[3];
    const float* b_attn    = (const float*)d_in[4];
    const float* W_proj    = (const float*)d_in[5];
    const float* b_proj    = (const float*)d_in[6];
    const float* decay_raw = (const float*)d_in[7];

    float* out_y = (float*)d_out;                  // 1024*2048
    float* out_k = out_y + 2097152;                // 16*2048*128
    float* out_v = out_y + 6291456;                // 16*2048*128

    char* ws = (char*)d_ws;
    if (ws_size < 63569920) return;
    // phase-1 regions
    u16*   WaT  = (u16*)(ws);                      // 6144x2048 bf16   25165824 B
    u16*   WpT  = (u16*)(ws + 25165824);           // 2048x2048 bf16    8388608 B (persists)
    u16*   Xb   = (u16*)(ws + 33554432);           // 1024x2048 bf16    4194304 B
    u16*   QKVb = (u16*)(ws + 37748736);           // 1024x6144 bf16   12582912 B
    float* BT   = (float*)(ws + 62914560);         // 16x2048 f32 (persists)
    float* CT   = (float*)(ws + 63045632);         // 1024x64 f32
    float* ST   = (float*)(ws + 63307776);         // 1024x64 f32
    // phase-2 aliases (dead regions reused)
    u16*   Qb   = (u16*)(ws);                      // in WaT   4194304 B
    u16*   Kb   = (u16*)(ws + 4194304);            // in WaT   8388608 B
    u16*   Vt   = (u16*)(ws + 12582912);           // in WaT   8388608 B
    u16*   Yb   = (u16*)(ws + 20971520);           // in WaT   4194304 B
    float* Pm   = (float*)(ws + 33554432);         // in Xb     262144 B
    float* Pl   = (float*)(ws + 33816576);         // in Xb     262144 B
    u16*   Pacc = (u16*)(ws + 37748736);           // over QKVb 16777216 B

    k_prep<<<6400, 256, 0, stream>>>(W_attn, W_proj, x, decay_raw, WaT, WpT, Xb, BT, CT, ST);
    k_gemm_bt<128, 64, 2, 2, u16><<<768, 256, 0, stream>>>(Xb, WaT, b_attn, QKVb, 1024, 6144, 2048);
    k_mid<<<13312, 256, 0, stream>>>(QKVb, CT, ST, cached_k, cached_v, Qb, Kb, out_k, out_v, Vt);
    k_attn<<<1024, 256, 0, stream>>>(Qb, Kb, Vt, BT, Pacc, Pm, Pl);
    k_merge<<<1024, 256, 0, stream>>>(Pacc, Pm, Pl, Yb);
    k_gemm_bt<64, 32, 2, 2, float><<<1024, 256, 0, stream>>>(Yb, WpT, b_proj, out_y, 1024, 2048, 2048);
}

// Round 17
// 133.214 us; speedup vs baseline: 1.2537x; 1.2537x over previous
//
#include <hip/hip_runtime.h>
#include <hip/hip_bf16.h>

typedef unsigned short u16;
typedef unsigned int u32;
typedef __attribute__((ext_vector_type(4))) float f32x4;
typedef float f32x4u __attribute__((ext_vector_type(4), aligned(4)));
typedef __attribute__((ext_vector_type(8))) short bf16x8;

__device__ __forceinline__ u16 f2bf(float f) {
    union { float f; u32 u; } v; v.f = f;
    return (u16)((v.u + 0x7FFFu + ((v.u >> 16) & 1u)) >> 16);
}
__device__ __forceinline__ float bf2f(u16 b) {
    union { u32 u; float f; } v; v.u = ((u32)b) << 16;
    return v.f;
}
__device__ __forceinline__ void st_out(float* p, float v) { *p = v; }
__device__ __forceinline__ void st_out(u16* p, float v) { *p = f2bf(v); }

__device__ __forceinline__ f32x4 mfma16(bf16x8 a, bf16x8 b, f32x4 c) {
    return __builtin_amdgcn_mfma_f32_16x16x32_bf16(a, b, c, 0, 0, 0);
}
__device__ __forceinline__ u32 cvt_pk_bf16(float lo, float hi) {
    u32 r;
    asm("v_cvt_pk_bf16_f32 %0, %1, %2" : "=v"(r) : "v"(lo), "v"(hi));
    return r;
}

#define GLD_LDS16(g, l) __builtin_amdgcn_global_load_lds( \
    (const __attribute__((address_space(1))) void*)(g),   \
    (__attribute__((address_space(3))) void*)(l), 16, 0, 0)

#define LOG2E 1.4426950408889634f
#define QSCALE 0.12751743f   /* (1/sqrt(128)) * log2e */

// ---------------- K_prep: tables + W transposes + x convert (fused) ----------------
__global__ __launch_bounds__(256) void k_prep(
    const float* __restrict__ W_attn, const float* __restrict__ W_proj,
    const float* __restrict__ x, const float* __restrict__ decay_raw,
    u16* __restrict__ WaT, u16* __restrict__ WpT, u16* __restrict__ Xb,
    float* __restrict__ bias_tab, float* __restrict__ cosT, float* __restrict__ sinT) {
    __shared__ float tile[64][65];
    const int b = blockIdx.x, tid = threadIdx.x;
    if (b < 4096) {
        // transpose f32 (R x Cc) -> bf16 (Cc x R)
        const float* src; u16* dst; int R, Cc, bx, by;
        if (b < 3072) { src = W_attn; dst = WaT; R = 2048; Cc = 6144; bx = b % 96; by = b / 96; }
        else          { src = W_proj; dst = WpT; R = 2048; Cc = 2048; bx = (b - 3072) & 31; by = (b - 3072) >> 5; }
        int c0 = bx * 64, r0 = by * 64;
        // vectorized float4 reads: 16 lanes cover one 256B tile row
#pragma unroll
        for (int it = 0; it < 4; ++it) {
            int idx = it * 256 + tid;              // 0..1023
            int r = idx >> 4, c4 = (idx & 15) * 4;
            float4 v = *(const float4*)(src + (size_t)(r0 + r) * Cc + c0 + c4);
            tile[r][c4]     = v.x; tile[r][c4 + 1] = v.y;
            tile[r][c4 + 2] = v.z; tile[r][c4 + 3] = v.w;
        }
        __syncthreads();
        // vectorized write: each thread packs 4 consecutive rr into uint2 (8B/lane)
#pragma unroll
        for (int it = 0; it < 4; ++it) {
            int idx = it * 256 + tid;              // 0..1023
            int cc = idx >> 4;                     // 0..63
            int rr0 = (idx & 15) * 4;
            u32 lo = (u32)f2bf(tile[rr0][cc])     | ((u32)f2bf(tile[rr0 + 1][cc]) << 16);
            u32 hi = (u32)f2bf(tile[rr0 + 2][cc]) | ((u32)f2bf(tile[rr0 + 3][cc]) << 16);
            uint2 p; p.x = lo; p.y = hi;
            *(uint2*)(dst + (size_t)(c0 + cc) * R + r0 + rr0) = p;
        }
    } else if (b < 6144) {
        int i = (b - 4096) * 256 + tid;          // 524288 float4s
        float4 v = ((const float4*)x)[i];
        u32 p0 = (u32)f2bf(v.x) | ((u32)f2bf(v.y) << 16);
        u32 p1 = (u32)f2bf(v.z) | ((u32)f2bf(v.w) << 16);
        uint2 p; p.x = p0; p.y = p1;
        *(uint2*)(Xb + (size_t)i * 4) = p;
    } else {
        int i = (b - 6144) * 256 + tid;
        if (i < 16 * 2048) {
            int h = i >> 11, dist = i & 2047;
            float dec = log1pf(expf(decay_raw[h]));
            bias_tab[i] = -log1pf(dec * log1pf((float)dist)) * LOG2E;   // log2 units
        }
        if (i < 1024 * 64) {
            int t = i >> 6, j = i & 63;
            float inv = expf(-logf(10000.0f) * (float)j / 64.0f);
            float ang = (float)(1024 + t) * inv;
            cosT[i] = cosf(ang);
            sinT[i] = sinf(ang);
        }
    }
}

// ---------------- GEMM: A (MxK) bf16 row-major, Bt (NxK) bf16 row-major ----------------
// Double-buffered 2-phase, ONE __syncthreads per tile (R4/R8/R14-proven stable).
// 1D grid with XCD-chunked swizzle: each XCD gets a contiguous N-slice (all M)
// so its B panel is L2-resident. Requires gridDim.x % 8 == 0.
template<int BM, int BN, int WRG, int WCG, typename OT>
__global__ __launch_bounds__(256) void k_gemm_bt(
    const u16* __restrict__ A, const u16* __restrict__ Bt,
    const float* __restrict__ bias, OT* __restrict__ C,
    int M, int N, int K) {
    constexpr int BK = 64;
    constexpr int WM = BM / WRG;
    constexpr int WN = BN / WCG;
    constexpr int MR = WM / 16;
    constexpr int NR = WN / 16;
    constexpr int LDSZ = (BM + BN) * BK * 2;
    __shared__ char lds[2][LDSZ];

    const int tid = threadIdx.x;
    const int lane = tid & 63, wid = tid >> 6;
    const int wr = wid / WCG, wc = wid % WCG;
    const int lhi = lane >> 4, llo = lane & 15;

    // XCD-chunked swizzle: xcd = bid % 8 gets work ids [xcd*per, (xcd+1)*per)
    const int per = gridDim.x >> 3;
    const int w = (blockIdx.x & 7) * per + (blockIdx.x >> 3);
    const int mblocks = M / BM;
    const int m0 = (w % mblocks) * BM, n0 = (w / mblocks) * BN;   // n-major chunks

    f32x4 acc[MR][NR];
#pragma unroll
    for (int m = 0; m < MR; ++m)
#pragma unroll
        for (int n = 0; n < NR; ++n)
            acc[m][n] = f32x4{0.f, 0.f, 0.f, 0.f};

    auto stage = [&](int buf, int k0) {
        char* ldsA = &lds[buf][0];
        char* ldsB = &lds[buf][0] + BM * BK * 2;
#pragma unroll
        for (int it = 0; it < (BM * 8) / 256; ++it) {
            int ci = it * 256 + wid * 64 + lane;
            int r = ci >> 3, c = ci & 7;
            int sc = c ^ (r & 7);
            GLD_LDS16(A + (size_t)(m0 + r) * K + k0 + sc * 8,
                      ldsA + (it * 256 + wid * 64) * 16);
        }
#pragma unroll
        for (int it = 0; it < (BN * 8) / 256; ++it) {
            int ci = it * 256 + wid * 64 + lane;
            int r = ci >> 3, c = ci & 7;
            int sc = c ^ (r & 7);
            GLD_LDS16(Bt + (size_t)(n0 + r) * K + k0 + sc * 8,
                      ldsB + (it * 256 + wid * 64) * 16);
        }
    };

    stage(0, 0);
    __syncthreads();
    int cur = 0;
    for (int k0 = 0; k0 < K; k0 += BK) {
        if (k0 + BK < K) stage(cur ^ 1, k0 + BK);
        const char* ldsA = &lds[cur][0];
        const char* ldsB = &lds[cur][0] + BM * BK * 2;
#pragma unroll
        for (int kk = 0; kk < BK; kk += 32) {
            bf16x8 af[MR], bfr[NR];
            const int clb = (kk >> 3) + lhi;
#pragma unroll
            for (int m = 0; m < MR; ++m) {
                int row = wr * WM + m * 16 + llo;
                af[m] = *(const bf16x8*)(ldsA + row * 128 + ((clb ^ (row & 7)) << 4));
            }
#pragma unroll
            for (int n = 0; n < NR; ++n) {
                int row = wc * WN + n * 16 + llo;
                bfr[n] = *(const bf16x8*)(ldsB + row * 128 + ((clb ^ (row & 7)) << 4));
            }
#pragma unroll
            for (int m = 0; m < MR; ++m)
#pragma unroll
                for (int n = 0; n < NR; ++n)
                    acc[m][n] = mfma16(af[m], bfr[n], acc[m][n]);
        }
        __syncthreads();
        cur ^= 1;
    }
#pragma unroll
    for (int m = 0; m < MR; ++m) {
        int row = m0 + wr * WM + m * 16 + lhi * 4;
#pragma unroll
        for (int n = 0; n < NR; ++n) {
            int col = n0 + wc * WN + n * 16 + llo;
            float bv = bias[col];
#pragma unroll
            for (int j = 0; j < 4; ++j)
                st_out(&C[(size_t)(row + j) * N + col], acc[m][n][j] + bv);
        }
    }
}

// ---------------- K_mid: RoPE q/k + cached K copy + V assemble (fused) ----------------
__global__ __launch_bounds__(256) void k_mid(
    const u16* __restrict__ qkv,
    const float* __restrict__ cosT, const float* __restrict__ sinT,
    const float* __restrict__ cached_k, const float* __restrict__ cached_v,
    u16* __restrict__ qb, u16* __restrict__ kb,
    float* __restrict__ out_k, float* __restrict__ out_v, u16* __restrict__ vt) {
    __shared__ u16 tile[64][65];
    const int b = blockIdx.x;
    if (b < 4096) {
        int i = b * 256 + threadIdx.x;             // 16*1024*64
        int j = i & 63;
        int t = (i >> 6) & 1023;
        int h = i >> 16;
        const u16* row = qkv + (size_t)t * 6144;
        float q1 = bf2f(row[h * 128 + j]),        q2 = bf2f(row[h * 128 + j + 64]);
        float k1 = bf2f(row[2048 + h * 128 + j]), k2 = bf2f(row[2048 + h * 128 + j + 64]);
        float cv = cosT[t * 64 + j], sv = sinT[t * 64 + j];
        float qo1 = q1 * cv - q2 * sv, qo2 = q1 * sv + q2 * cv;
        float ko1 = k1 * cv - k2 * sv, ko2 = k1 * sv + k2 * cv;
        size_t qoff = ((size_t)h * 1024 + t) * 128 + j;
        qb[qoff] = f2bf(qo1 * QSCALE); qb[qoff + 64] = f2bf(qo2 * QSCALE);
        size_t koff = ((size_t)h * 2048 + 1024 + t) * 128 + j;
        kb[koff] = f2bf(ko1); kb[koff + 64] = f2bf(ko2);
        out_k[koff] = ko1; out_k[koff + 64] = ko2;
    } else if (b < 12288) {
        int i = (b - 4096) * 256 + threadIdx.x;    // 16*1024*128
        int d = i & 127, s = (i >> 7) & 1023, h = i >> 17;
        float v = cached_k[i];
        size_t off = ((size_t)h * 2048 + s) * 128 + d;
        out_k[off] = v;
        kb[off] = f2bf(v);
    } else {
        // V assemble: out_v f32 + per-head transposed bf16
        int idx2 = b - 12288;                      // 1024 blocks
        int s0 = (idx2 & 31) * 64, d0 = ((idx2 >> 5) & 1) * 64, h = idx2 >> 6;
        int tid = threadIdx.x;
#pragma unroll
        for (int it = 0; it < 16; ++it) {
            int idx = it * 256 + tid;
            int r = idx >> 6, c = idx & 63;
            int s = s0 + r, d = d0 + c;
            u16 v = (s < 1024)
                ? f2bf(cached_v[((size_t)h * 1024 + s) * 128 + d])
                : qkv[(size_t)(s - 1024) * 6144 + 4096 + h * 128 + d];
            tile[r][c] = v;
            out_v[((size_t)h * 2048 + s) * 128 + d] = bf2f(v);
        }
        __syncthreads();
        // vectorized transpose write: 4 consecutive ss per thread -> uint2
#pragma unroll
        for (int it = 0; it < 4; ++it) {
            int idx = it * 256 + tid;              // 0..1023
            int dd = idx >> 4;                     // 0..63
            int ss0 = (idx & 15) * 4;
            u32 lo = (u32)tile[ss0][dd]     | ((u32)tile[ss0 + 1][dd] << 16);
            u32 hi = (u32)tile[ss0 + 2][dd] | ((u32)tile[ss0 + 3][dd] << 16);
            uint2 p; p.x = lo; p.y = hi;
            *(uint2*)(vt + ((size_t)h * 128 + d0 + dd) * 2048 + s0 + ss0) = p;
        }
    }
}

// ---------------- K4: flash attention v5b (R14-proven LDS-V __syncthreads version) ----------------
// 4 waves x 16 q-rows, 4-way split-S (grid 1024 = 4 blocks/CU), qt-descending,
// KVBLK=32 dbuf, swapped QK^T, lane-local softmax, in-register P (cvt_pk +
// xor16/32/48 permute, no ldsP), lrow summed from the SAME bf16 P used in PV.
__global__ __launch_bounds__(256, 4) void k_attn(
    const u16* __restrict__ qb,   // [16][1024][128], pre-scaled
    const u16* __restrict__ kb,   // [16][2048][128]
    const u16* __restrict__ vt,   // [16][128][2048]
    const float* __restrict__ bias_tab, // [16][2048], log2 units
    u16* __restrict__ Pacc,       // [1024 slots][64][128] bf16
    float* __restrict__ Pm,       // [1024 slots][64]
    float* __restrict__ Pl) {     // [1024 slots][64]
    __shared__ char ldsK[2][32 * 256];   // 8 KB each
    __shared__ char ldsV[2][128 * 64];   // 8 KB each

    const int bid = blockIdx.x;
    const int xcd = bid & 7, idx = bid >> 3;
    const int work = xcd * 128 + idx;              // 2 heads per XCD
    const int h = work >> 6, rem = work & 63;
    const int qt = 15 - (rem >> 2), chunk = rem & 3;   // qt descending: big first
    const int qbase = qt * 64;
    const int tid = threadIdx.x, lane = tid & 63, wid = tid >> 6;
    const int lhi = lane >> 4, llo = lane & 15;
    const int slot = (h * 16 + qt) * 4 + chunk;

    const u16* kg = kb + (size_t)h * 2048 * 128;
    const u16* vg = vt + (size_t)h * 128 * 2048;
    const float* bt = bias_tab + h * 2048;

    // Q as B-operand fragment: col (n) = llo = q, k-chunks per lhi
    bf16x8 qf[4];
    {
        const u16* qrow = qb + ((size_t)h * 1024 + qbase + wid * 16 + llo) * 128;
#pragma unroll
        for (int c = 0; c < 4; ++c)
            qf[c] = *(const bf16x8*)(qrow + c * 32 + lhi * 8);
    }

    f32x4 acc[8];
#pragma unroll
    for (int d = 0; d < 8; ++d) acc[d] = f32x4{0.f, 0.f, 0.f, 0.f};
    float mrow = -3e38f;      // running max for q = llo (uniform across lhi groups)
    float lrow = 0.f;         // per-lane partial sum (reduced across lhi at end)

    const int ntiles = 34 + 2 * qt;                // 32-key tiles
    const int qpos = 1024 + qbase + wid * 16 + llo;

    auto stage = [&](int b, int st) {
        int sbase = st * 32;
#pragma unroll
        for (int it = 0; it < 2; ++it) {           // K: 32 rows x 16 chunks of 16B
            int ci = it * 256 + tid;
            int r = ci >> 4, c = ci & 15;
            int sc = c ^ (r & 7);
            GLD_LDS16(kg + (size_t)(sbase + r) * 128 + sc * 8,
                      &ldsK[b][0] + (it * 256 + wid * 64) * 16);
        }
#pragma unroll
        for (int it = 0; it < 2; ++it) {           // V: 128 rows x 4 chunks of 16B
            int ci = it * 256 + tid;
            int r = ci >> 2, c = ci & 3;
            int sc = c ^ ((r >> 1) & 3);
            GLD_LDS16(vg + (size_t)r * 2048 + sbase + sc * 8,
                      &ldsV[b][0] + (it * 256 + wid * 64) * 16);
        }
    };

    // in-register P permutation: p0..p3 hold keys {lhi*4+0,1},{2,3},{16+lhi*4+0,1},{2,3}
    // for q=llo -> A-fragment (row=q=llo, keys lhi*8..lhi*8+7) via xor16/32/48 exchanges
    auto permP = [&](u32 p0, u32 p1, u32 p2, u32 p3) -> bf16x8 {
        u32 r16a = (u32)__shfl_xor((int)(lhi == 1 ? p0 : p2), 16);
        u32 r16b = (u32)__shfl_xor((int)(lhi == 1 ? p1 : p3), 16);
        u32 r32a = (u32)__shfl_xor((int)(lhi == 3 ? p0 : p2), 32);
        u32 r32b = (u32)__shfl_xor((int)(lhi == 3 ? p1 : p3), 32);
        u32 r48a = (u32)__shfl_xor((int)(lhi == 2 ? p0 : p2), 48);
        u32 r48b = (u32)__shfl_xor((int)(lhi == 2 ? p1 : p3), 48);
        union { u32 w[4]; bf16x8 v; } u;
        u.w[0] = lhi == 0 ? p0 : lhi == 1 ? r48a : lhi == 2 ? r32a : r16a;
        u.w[1] = lhi == 0 ? p1 : lhi == 1 ? r48b : lhi == 2 ? r32b : r16b;
        u.w[2] = lhi == 0 ? r16a : lhi == 1 ? r32a : lhi == 2 ? r48a : p2;
        u.w[3] = lhi == 0 ? r16b : lhi == 1 ? r32b : lhi == 2 ? r48b : p3;
        return u.v;
    };

    // descending tile order: near-diagonal (high-bias) first -> few rescales
    const int st0 = chunk + 4 * ((ntiles - 1 - chunk) >> 2);
    stage(0, st0);
    __syncthreads();
    int cur = 0;
    for (int st = st0; st >= chunk; st -= 4) {
        if (st >= chunk + 4) stage(cur ^ 1, st - 4);
        const int sbase = st * 32;
        const char* lK = &ldsK[cur][0];
        const char* lV = &ldsV[cur][0];

        // bias windows: dist = qpos - (sbase + sub*16 + lhi*4 + j)
        const int D0 = qpos - sbase - lhi * 4;
        f32x4u wB = *(const f32x4u*)(bt + (D0 - 3 < 0 ? 0 : D0 - 3));
        f32x4u wC = *(const f32x4u*)(bt + (D0 - 19 < 0 ? 0 : D0 - 19));

        // swapped QK^T: A = K rows (keys), B = Q (q = llo)
        f32x4 sc4[2];
        __builtin_amdgcn_s_setprio(1);
#pragma unroll
        for (int sub = 0; sub < 2; ++sub) {
            f32x4 s4 = f32x4{0.f, 0.f, 0.f, 0.f};
            int key = sub * 16 + llo;
#pragma unroll
            for (int c2 = 0; c2 < 4; ++c2) {
                int cl = c2 * 4 + lhi;
                bf16x8 kf = *(const bf16x8*)(lK + key * 256 + ((cl ^ (key & 7)) << 4));
                s4 = mfma16(kf, qf[c2], s4);
            }
            sc4[sub] = s4;
        }
        __builtin_amdgcn_s_setprio(0);

        // bias + causal mask (wave-uniform branch; only diagonal tiles mask)
        if (sbase + 31 <= 1024 + qbase + wid * 16) {
#pragma unroll
            for (int j = 0; j < 4; ++j) {
                sc4[0][j] += wB[3 - j];
                sc4[1][j] += wC[3 - j];
            }
        } else {
#pragma unroll
            for (int sub = 0; sub < 2; ++sub)
#pragma unroll
                for (int j = 0; j < 4; ++j) {
                    int key = sbase + sub * 16 + lhi * 4 + j;
                    int dist = qpos - key;
                    float bv = bt[dist < 0 ? 0 : dist];
                    sc4[sub][j] = (dist < 0) ? -3e38f : sc4[sub][j] + bv;
                }
        }

        // defer-max (base-2): lane-local max over 8 keys; rescale past threshold only
        float tmax = fmaxf(fmaxf(fmaxf(sc4[0][0], sc4[0][1]), fmaxf(sc4[0][2], sc4[0][3])),
                           fmaxf(fmaxf(sc4[1][0], sc4[1][1]), fmaxf(sc4[1][2], sc4[1][3])));
        int ok = (tmax <= mrow + 8.0f) ? 1 : 0;
        if (!__all(ok)) {
            float t = tmax;
            t = fmaxf(t, __shfl_xor(t, 16));
            t = fmaxf(t, __shfl_xor(t, 32));
            float mnew = fmaxf(mrow, t);
            float fs = exp2f(mrow - mnew);
            mrow = mnew;
            lrow *= fs;
            float fsj[4];
#pragma unroll
            for (int j = 0; j < 4; ++j)
                fsj[j] = __shfl(fs, lhi * 4 + j);   // acc rows: q = lhi*4+j
#pragma unroll
            for (int d = 0; d < 8; ++d)
#pragma unroll
                for (int j = 0; j < 4; ++j) acc[d][j] *= fsj[j];
        }

        // P = 2^(s-m) in-register; pack to bf16; lrow sums the PACKED values
        float p[8];
#pragma unroll
        for (int sub = 0; sub < 2; ++sub)
#pragma unroll
            for (int j = 0; j < 4; ++j)
                p[sub * 4 + j] = exp2f(sc4[sub][j] - mrow);
        u32 pk0 = cvt_pk_bf16(p[0], p[1]), pk1 = cvt_pk_bf16(p[2], p[3]);
        u32 pk2 = cvt_pk_bf16(p[4], p[5]), pk3 = cvt_pk_bf16(p[6], p[7]);
        lrow += bf2f((u16)(pk0 & 0xFFFF)) + bf2f((u16)(pk0 >> 16))
              + bf2f((u16)(pk1 & 0xFFFF)) + bf2f((u16)(pk1 >> 16))
              + bf2f((u16)(pk2 & 0xFFFF)) + bf2f((u16)(pk2 >> 16))
              + bf2f((u16)(pk3 & 0xFFFF)) + bf2f((u16)(pk3 >> 16));
        bf16x8 pa = permP(pk0, pk1, pk2, pk3);

        // PV: A = P (rows = q), B = V^T rows = d
        __builtin_amdgcn_s_setprio(1);
#pragma unroll
        for (int db = 0; db < 8; ++db) {
            int dr = db * 16 + llo;
            int cl = lhi ^ ((dr >> 1) & 3);
            bf16x8 vf = *(const bf16x8*)(lV + dr * 64 + cl * 16);
            acc[db] = mfma16(pa, vf, acc[db]);
        }
        __builtin_amdgcn_s_setprio(0);
        __syncthreads();
        cur ^= 1;
    }

    // final sum-reduce of per-lane lrow partials across lhi groups
    {
        float t = lrow;
        t += __shfl_xor(t, 16);
        t += __shfl_xor(t, 32);
        lrow = t;
    }

    if (lhi == 0) {
        int r = wid * 16 + llo;
        Pm[(size_t)slot * 64 + r] = mrow;
        Pl[(size_t)slot * 64 + r] = lrow;
    }
#pragma unroll
    for (int db = 0; db < 8; ++db)
#pragma unroll
        for (int j = 0; j < 4; ++j) {
            int r = wid * 16 + lhi * 4 + j;        // q row
            Pacc[(size_t)slot * 8192 + r * 128 + db * 16 + llo] = f2bf(acc[db][j]);
        }
}

// ---------------- K4b: merge 4-way split-S partials (1024 blocks, 4/CU) ----------------
__global__ __launch_bounds__(256) void k_merge(
    const u16* __restrict__ Pacc, const float* __restrict__ Pm,
    const float* __restrict__ Pl, u16* __restrict__ yb) {
    const int b = blockIdx.x;
    const int h = b >> 6, qt = (b >> 2) & 15, quarter = b & 3;
    const int slot0 = (h * 16 + qt) * 4;
    const int tid = threadIdx.x;
    const int r = tid >> 2, dd = (tid & 3) * 8 + quarter * 32;

    float m[4], l[4];
#pragma unroll
    for (int c = 0; c < 4; ++c) {
        m[c] = Pm[(size_t)(slot0 + c) * 64 + r];
        l[c] = Pl[(size_t)(slot0 + c) * 64 + r];
    }
    float M = fmaxf(fmaxf(m[0], m[1]), fmaxf(m[2], m[3]));
    float w[4], L = 0.f;
#pragma unroll
    for (int c = 0; c < 4; ++c) {
        w[c] = exp2f(m[c] - M);
        L += w[c] * l[c];
    }
    float inv = 1.0f / L;

    float y[8];
#pragma unroll
    for (int i = 0; i < 8; ++i) y[i] = 0.f;
#pragma unroll
    for (int c = 0; c < 4; ++c) {
        const uint4* pa = (const uint4*)(Pacc + (size_t)(slot0 + c) * 8192 + r * 128 + dd);
        float wc = w[c];
        uint4 v = *pa;
        u32 a[4] = {v.x, v.y, v.z, v.w};
#pragma unroll
        for (int p = 0; p < 4; ++p) {
            y[p * 2]     += wc * bf2f((u16)(a[p] & 0xFFFF));
            y[p * 2 + 1] += wc * bf2f((u16)(a[p] >> 16));
        }
    }
    int trow = qt * 64 + r;
    uint4 outv;
    u32* ow = (u32*)&outv;
#pragma unroll
    for (int k = 0; k < 4; ++k)
        ow[k] = (u32)f2bf(y[2 * k] * inv) | ((u32)f2bf(y[2 * k + 1] * inv) << 16);
    *(uint4*)(yb + (size_t)trow * 2048 + h * 128 + dd) = outv;
}

// ---------------- launch ----------------
extern "C" void kernel_launch(void* const* d_in, const int* in_sizes, int n_in,
                              void* d_out, int out_size, void* d_ws, size_t ws_size,
                              hipStream_t stream) {
    (void)in_sizes; (void)n_in; (void)out_size;
    const float* x         = (const float*)d_in[0];
    const float* cached_k  = (const float*)d_in[1];
    const float* cached_v  = (const float*)d_in[2];
    const float* W_attn    = (const float*)d_in[3];
    const float* b_attn    = (const float*)d_in[4];
    const float* W_proj    = (const float*)d_in[5];
    const float* b_proj    = (const float*)d_in[6];
    const float* decay_raw = (const float*)d_in[7];

    float* out_y = (float*)d_out;                  // 1024*2048
    float* out_k = out_y + 2097152;                // 16*2048*128
    float* out_v = out_y + 6291456;                // 16*2048*128

    char* ws = (char*)d_ws;
    if (ws_size < 63569920) return;
    // phase-1 regions
    u16*   WaT  = (u16*)(ws);                      // 6144x2048 bf16   25165824 B
    u16*   WpT  = (u16*)(ws + 25165824);           // 2048x2048 bf16    8388608 B (persists)
    u16*   Xb   = (u16*)(ws + 33554432);           // 1024x2048 bf16    4194304 B
    u16*   QKVb = (u16*)(ws + 37748736);           // 1024x6144 bf16   12582912 B
    float* BT   = (float*)(ws + 62914560);         // 16x2048 f32 (persists)
    float* CT   = (float*)(ws + 63045632);         // 1024x64 f32
    float* ST   = (float*)(ws + 63307776);         // 1024x64 f32
    // phase-2 aliases (dead regions reused)
    u16*   Qb   = (u16*)(ws);                      // in WaT   4194304 B
    u16*   Kb   = (u16*)(ws + 4194304);            // in WaT   8388608 B
    u16*   Vt   = (u16*)(ws + 12582912);           // in WaT   8388608 B
    u16*   Yb   = (u16*)(ws + 20971520);           // in WaT   4194304 B
    float* Pm   = (float*)(ws + 33554432);         // in Xb     262144 B
    float* Pl   = (float*)(ws + 33816576);         // in Xb     262144 B
    u16*   Pacc = (u16*)(ws + 37748736);           // over QKVb 16777216 B

    k_prep<<<6400, 256, 0, stream>>>(W_attn, W_proj, x, decay_raw, WaT, WpT, Xb, BT, CT, ST);
    k_gemm_bt<128, 64, 2, 2, u16><<<768, 256, 0, stream>>>(Xb, WaT, b_attn, QKVb, 1024, 6144, 2048);
    k_mid<<<13312, 256, 0, stream>>>(QKVb, CT, ST, cached_k, cached_v, Qb, Kb, out_k, out_v, Vt);
    k_attn<<<1024, 256, 0, stream>>>(Qb, Kb, Vt, BT, Pacc, Pm, Pl);
    k_merge<<<1024, 256, 0, stream>>>(Pacc, Pm, Pl, Yb);
    k_gemm_bt<64, 32, 2, 2, float><<<1024, 256, 0, stream>>>(Yb, WpT, b_proj, out_y, 1024, 2048, 2048);
}

// Round 18
// 131.778 us; speedup vs baseline: 1.2673x; 1.0109x over previous
//
#include <hip/hip_runtime.h>
#include <hip/hip_bf16.h>

typedef unsigned short u16;
typedef unsigned int u32;
typedef __attribute__((ext_vector_type(4))) float f32x4;
typedef float f32x4u __attribute__((ext_vector_type(4), aligned(4)));
typedef __attribute__((ext_vector_type(8))) short bf16x8;

__device__ __forceinline__ u16 f2bf(float f) {
    union { float f; u32 u; } v; v.f = f;
    return (u16)((v.u + 0x7FFFu + ((v.u >> 16) & 1u)) >> 16);
}
__device__ __forceinline__ float bf2f(u16 b) {
    union { u32 u; float f; } v; v.u = ((u32)b) << 16;
    return v.f;
}
__device__ __forceinline__ void st_out(float* p, float v) { *p = v; }
__device__ __forceinline__ void st_out(u16* p, float v) { *p = f2bf(v); }

__device__ __forceinline__ f32x4 mfma16(bf16x8 a, bf16x8 b, f32x4 c) {
    return __builtin_amdgcn_mfma_f32_16x16x32_bf16(a, b, c, 0, 0, 0);
}
__device__ __forceinline__ u32 cvt_pk_bf16(float lo, float hi) {
    u32 r;
    asm("v_cvt_pk_bf16_f32 %0, %1, %2" : "=v"(r) : "v"(lo), "v"(hi));
    return r;
}

#define GLD_LDS16(g, l) __builtin_amdgcn_global_load_lds( \
    (const __attribute__((address_space(1))) void*)(g),   \
    (__attribute__((address_space(3))) void*)(l), 16, 0, 0)

#define LOG2E 1.4426950408889634f
#define QSCALE 0.12751743f   /* (1/sqrt(128)) * log2e */

// ---------------- K_prep: tables + W transposes + x convert (fused) ----------------
__global__ __launch_bounds__(256) void k_prep(
    const float* __restrict__ W_attn, const float* __restrict__ W_proj,
    const float* __restrict__ x, const float* __restrict__ decay_raw,
    u16* __restrict__ WaT, u16* __restrict__ WpT, u16* __restrict__ Xb,
    float* __restrict__ bias_tab, float* __restrict__ cosT, float* __restrict__ sinT) {
    __shared__ float tile[64][65];
    const int b = blockIdx.x, tid = threadIdx.x;
    if (b < 4096) {
        // transpose f32 (R x Cc) -> bf16 (Cc x R)
        const float* src; u16* dst; int R, Cc, bx, by;
        if (b < 3072) { src = W_attn; dst = WaT; R = 2048; Cc = 6144; bx = b % 96; by = b / 96; }
        else          { src = W_proj; dst = WpT; R = 2048; Cc = 2048; bx = (b - 3072) & 31; by = (b - 3072) >> 5; }
        int c0 = bx * 64, r0 = by * 64;
        // vectorized float4 reads: 16 lanes cover one 256B tile row
#pragma unroll
        for (int it = 0; it < 4; ++it) {
            int idx = it * 256 + tid;              // 0..1023
            int r = idx >> 4, c4 = (idx & 15) * 4;
            float4 v = *(const float4*)(src + (size_t)(r0 + r) * Cc + c0 + c4);
            tile[r][c4]     = v.x; tile[r][c4 + 1] = v.y;
            tile[r][c4 + 2] = v.z; tile[r][c4 + 3] = v.w;
        }
        __syncthreads();
        // vectorized write: each thread packs 4 consecutive rr into uint2 (8B/lane)
#pragma unroll
        for (int it = 0; it < 4; ++it) {
            int idx = it * 256 + tid;              // 0..1023
            int cc = idx >> 4;                     // 0..63
            int rr0 = (idx & 15) * 4;
            u32 lo = (u32)f2bf(tile[rr0][cc])     | ((u32)f2bf(tile[rr0 + 1][cc]) << 16);
            u32 hi = (u32)f2bf(tile[rr0 + 2][cc]) | ((u32)f2bf(tile[rr0 + 3][cc]) << 16);
            uint2 p; p.x = lo; p.y = hi;
            *(uint2*)(dst + (size_t)(c0 + cc) * R + r0 + rr0) = p;
        }
    } else if (b < 6144) {
        int i = (b - 4096) * 256 + tid;          // 524288 float4s
        float4 v = ((const float4*)x)[i];
        u32 p0 = (u32)f2bf(v.x) | ((u32)f2bf(v.y) << 16);
        u32 p1 = (u32)f2bf(v.z) | ((u32)f2bf(v.w) << 16);
        uint2 p; p.x = p0; p.y = p1;
        *(uint2*)(Xb + (size_t)i * 4) = p;
    } else {
        int i = (b - 6144) * 256 + tid;
        if (i < 16 * 2048) {
            int h = i >> 11, dist = i & 2047;
            float dec = log1pf(expf(decay_raw[h]));
            bias_tab[i] = -log1pf(dec * log1pf((float)dist)) * LOG2E;   // log2 units
        }
        if (i < 1024 * 64) {
            int t = i >> 6, j = i & 63;
            float inv = expf(-logf(10000.0f) * (float)j / 64.0f);
            float ang = (float)(1024 + t) * inv;
            cosT[i] = cosf(ang);
            sinT[i] = sinf(ang);
        }
    }
}

// ---------------- GEMM: A (MxK) bf16 row-major, Bt (NxK) bf16 row-major ----------------
// Double-buffered 2-phase, ONE __syncthreads per tile (R4/R8/R14-proven stable).
// 1D grid with XCD-chunked swizzle: each XCD gets a contiguous N-slice (all M)
// so its B panel is L2-resident. Requires gridDim.x % 8 == 0.
template<int BM, int BN, int WRG, int WCG, typename OT>
__global__ __launch_bounds__(256) void k_gemm_bt(
    const u16* __restrict__ A, const u16* __restrict__ Bt,
    const float* __restrict__ bias, OT* __restrict__ C,
    int M, int N, int K) {
    constexpr int BK = 64;
    constexpr int WM = BM / WRG;
    constexpr int WN = BN / WCG;
    constexpr int MR = WM / 16;
    constexpr int NR = WN / 16;
    constexpr int LDSZ = (BM + BN) * BK * 2;
    __shared__ char lds[2][LDSZ];

    const int tid = threadIdx.x;
    const int lane = tid & 63, wid = tid >> 6;
    const int wr = wid / WCG, wc = wid % WCG;
    const int lhi = lane >> 4, llo = lane & 15;

    // XCD-chunked swizzle: xcd = bid % 8 gets work ids [xcd*per, (xcd+1)*per)
    const int per = gridDim.x >> 3;
    const int w = (blockIdx.x & 7) * per + (blockIdx.x >> 3);
    const int mblocks = M / BM;
    const int m0 = (w % mblocks) * BM, n0 = (w / mblocks) * BN;   // n-major chunks

    f32x4 acc[MR][NR];
#pragma unroll
    for (int m = 0; m < MR; ++m)
#pragma unroll
        for (int n = 0; n < NR; ++n)
            acc[m][n] = f32x4{0.f, 0.f, 0.f, 0.f};

    auto stage = [&](int buf, int k0) {
        char* ldsA = &lds[buf][0];
        char* ldsB = &lds[buf][0] + BM * BK * 2;
#pragma unroll
        for (int it = 0; it < (BM * 8) / 256; ++it) {
            int ci = it * 256 + wid * 64 + lane;
            int r = ci >> 3, c = ci & 7;
            int sc = c ^ (r & 7);
            GLD_LDS16(A + (size_t)(m0 + r) * K + k0 + sc * 8,
                      ldsA + (it * 256 + wid * 64) * 16);
        }
#pragma unroll
        for (int it = 0; it < (BN * 8) / 256; ++it) {
            int ci = it * 256 + wid * 64 + lane;
            int r = ci >> 3, c = ci & 7;
            int sc = c ^ (r & 7);
            GLD_LDS16(Bt + (size_t)(n0 + r) * K + k0 + sc * 8,
                      ldsB + (it * 256 + wid * 64) * 16);
        }
    };

    stage(0, 0);
    __syncthreads();
    int cur = 0;
    for (int k0 = 0; k0 < K; k0 += BK) {
        if (k0 + BK < K) stage(cur ^ 1, k0 + BK);
        const char* ldsA = &lds[cur][0];
        const char* ldsB = &lds[cur][0] + BM * BK * 2;
#pragma unroll
        for (int kk = 0; kk < BK; kk += 32) {
            bf16x8 af[MR], bfr[NR];
            const int clb = (kk >> 3) + lhi;
#pragma unroll
            for (int m = 0; m < MR; ++m) {
                int row = wr * WM + m * 16 + llo;
                af[m] = *(const bf16x8*)(ldsA + row * 128 + ((clb ^ (row & 7)) << 4));
            }
#pragma unroll
            for (int n = 0; n < NR; ++n) {
                int row = wc * WN + n * 16 + llo;
                bfr[n] = *(const bf16x8*)(ldsB + row * 128 + ((clb ^ (row & 7)) << 4));
            }
#pragma unroll
            for (int m = 0; m < MR; ++m)
#pragma unroll
                for (int n = 0; n < NR; ++n)
                    acc[m][n] = mfma16(af[m], bfr[n], acc[m][n]);
        }
        __syncthreads();
        cur ^= 1;
    }
#pragma unroll
    for (int m = 0; m < MR; ++m) {
        int row = m0 + wr * WM + m * 16 + lhi * 4;
#pragma unroll
        for (int n = 0; n < NR; ++n) {
            int col = n0 + wc * WN + n * 16 + llo;
            float bv = bias[col];
#pragma unroll
            for (int j = 0; j < 4; ++j)
                st_out(&C[(size_t)(row + j) * N + col], acc[m][n][j] + bv);
        }
    }
}

// ---------------- K_mid: RoPE q/k + cached K copy + V assemble (fused, vectorized) ----------------
__global__ __launch_bounds__(256) void k_mid(
    const u16* __restrict__ qkv,
    const float* __restrict__ cosT, const float* __restrict__ sinT,
    const float* __restrict__ cached_k, const float* __restrict__ cached_v,
    u16* __restrict__ qb, u16* __restrict__ kb,
    float* __restrict__ out_k, float* __restrict__ out_v, u16* __restrict__ vt) {
    __shared__ u16 tile[64][65];
    const int b = blockIdx.x;
    if (b < 1024) {
        // RoPE: 4 consecutive j per thread (vectorized loads/stores)
        int e = b * 256 + threadIdx.x;             // 0..262143
        int j0 = (e & 15) * 4;
        int t = (e >> 4) & 1023;
        int h = e >> 14;
        const u16* row = qkv + (size_t)t * 6144;
        uint2 q1v = *(const uint2*)(row + h * 128 + j0);
        uint2 q2v = *(const uint2*)(row + h * 128 + j0 + 64);
        uint2 k1v = *(const uint2*)(row + 2048 + h * 128 + j0);
        uint2 k2v = *(const uint2*)(row + 2048 + h * 128 + j0 + 64);
        float4 cv4 = *(const float4*)(cosT + t * 64 + j0);
        float4 sv4 = *(const float4*)(sinT + t * 64 + j0);
        float q1[4] = { bf2f((u16)(q1v.x & 0xFFFF)), bf2f((u16)(q1v.x >> 16)),
                        bf2f((u16)(q1v.y & 0xFFFF)), bf2f((u16)(q1v.y >> 16)) };
        float q2[4] = { bf2f((u16)(q2v.x & 0xFFFF)), bf2f((u16)(q2v.x >> 16)),
                        bf2f((u16)(q2v.y & 0xFFFF)), bf2f((u16)(q2v.y >> 16)) };
        float k1[4] = { bf2f((u16)(k1v.x & 0xFFFF)), bf2f((u16)(k1v.x >> 16)),
                        bf2f((u16)(k1v.y & 0xFFFF)), bf2f((u16)(k1v.y >> 16)) };
        float k2[4] = { bf2f((u16)(k2v.x & 0xFFFF)), bf2f((u16)(k2v.x >> 16)),
                        bf2f((u16)(k2v.y & 0xFFFF)), bf2f((u16)(k2v.y >> 16)) };
        float cv[4] = { cv4.x, cv4.y, cv4.z, cv4.w };
        float sv[4] = { sv4.x, sv4.y, sv4.z, sv4.w };
        float qo1[4], qo2[4], ko1[4], ko2[4];
#pragma unroll
        for (int u = 0; u < 4; ++u) {
            qo1[u] = q1[u] * cv[u] - q2[u] * sv[u];
            qo2[u] = q1[u] * sv[u] + q2[u] * cv[u];
            ko1[u] = k1[u] * cv[u] - k2[u] * sv[u];
            ko2[u] = k1[u] * sv[u] + k2[u] * cv[u];
        }
        size_t qoff = ((size_t)h * 1024 + t) * 128 + j0;
        uint2 pq1, pq2, pk1o, pk2o;
        pq1.x = (u32)f2bf(qo1[0] * QSCALE) | ((u32)f2bf(qo1[1] * QSCALE) << 16);
        pq1.y = (u32)f2bf(qo1[2] * QSCALE) | ((u32)f2bf(qo1[3] * QSCALE) << 16);
        pq2.x = (u32)f2bf(qo2[0] * QSCALE) | ((u32)f2bf(qo2[1] * QSCALE) << 16);
        pq2.y = (u32)f2bf(qo2[2] * QSCALE) | ((u32)f2bf(qo2[3] * QSCALE) << 16);
        *(uint2*)(qb + qoff) = pq1;
        *(uint2*)(qb + qoff + 64) = pq2;
        size_t koff = ((size_t)h * 2048 + 1024 + t) * 128 + j0;
        pk1o.x = (u32)f2bf(ko1[0]) | ((u32)f2bf(ko1[1]) << 16);
        pk1o.y = (u32)f2bf(ko1[2]) | ((u32)f2bf(ko1[3]) << 16);
        pk2o.x = (u32)f2bf(ko2[0]) | ((u32)f2bf(ko2[1]) << 16);
        pk2o.y = (u32)f2bf(ko2[2]) | ((u32)f2bf(ko2[3]) << 16);
        *(uint2*)(kb + koff) = pk1o;
        *(uint2*)(kb + koff + 64) = pk2o;
        float4 o1; o1.x = ko1[0]; o1.y = ko1[1]; o1.z = ko1[2]; o1.w = ko1[3];
        float4 o2; o2.x = ko2[0]; o2.y = ko2[1]; o2.z = ko2[2]; o2.w = ko2[3];
        *(float4*)(out_k + koff) = o1;
        *(float4*)(out_k + koff + 64) = o2;
    } else if (b < 3072) {
        // cached K copy: 4 consecutive d per thread
        int e = (b - 1024) * 256 + threadIdx.x;    // 0..524287
        size_t i0 = (size_t)e * 4;
        int d0 = (int)(i0 & 127);
        int s = (int)((i0 >> 7) & 1023);
        int h = (int)(i0 >> 17);
        float4 v = *(const float4*)(cached_k + i0);
        size_t off = ((size_t)h * 2048 + s) * 128 + d0;
        *(float4*)(out_k + off) = v;
        uint2 p;
        p.x = (u32)f2bf(v.x) | ((u32)f2bf(v.y) << 16);
        p.y = (u32)f2bf(v.z) | ((u32)f2bf(v.w) << 16);
        *(uint2*)(kb + off) = p;
    } else {
        // V assemble: out_v f32 + per-head transposed bf16
        int idx2 = b - 3072;                       // 1024 blocks
        int s0 = (idx2 & 31) * 64, d0 = ((idx2 >> 5) & 1) * 64, h = idx2 >> 6;
        int tid = threadIdx.x;
#pragma unroll
        for (int it = 0; it < 16; ++it) {
            int idx = it * 256 + tid;
            int r = idx >> 6, c = idx & 63;
            int s = s0 + r, d = d0 + c;
            u16 v = (s < 1024)
                ? f2bf(cached_v[((size_t)h * 1024 + s) * 128 + d])
                : qkv[(size_t)(s - 1024) * 6144 + 4096 + h * 128 + d];
            tile[r][c] = v;
            out_v[((size_t)h * 2048 + s) * 128 + d] = bf2f(v);
        }
        __syncthreads();
        // vectorized transpose write: 4 consecutive ss per thread -> uint2
#pragma unroll
        for (int it = 0; it < 4; ++it) {
            int idx = it * 256 + tid;              // 0..1023
            int dd = idx >> 4;                     // 0..63
            int ss0 = (idx & 15) * 4;
            u32 lo = (u32)tile[ss0][dd]     | ((u32)tile[ss0 + 1][dd] << 16);
            u32 hi = (u32)tile[ss0 + 2][dd] | ((u32)tile[ss0 + 3][dd] << 16);
            uint2 p; p.x = lo; p.y = hi;
            *(uint2*)(vt + ((size_t)h * 128 + d0 + dd) * 2048 + s0 + ss0) = p;
        }
    }
}

// ---------------- K4: flash attention v5b (R14/R17-proven LDS-V __syncthreads version) ----------------
// 4 waves x 16 q-rows, 4-way split-S (grid 1024 = 4 blocks/CU), qt-descending,
// KVBLK=32 dbuf, swapped QK^T, lane-local softmax, in-register P (cvt_pk +
// xor16/32/48 permute, no ldsP), lrow summed from the SAME bf16 P used in PV.
__global__ __launch_bounds__(256, 4) void k_attn(
    const u16* __restrict__ qb,   // [16][1024][128], pre-scaled
    const u16* __restrict__ kb,   // [16][2048][128]
    const u16* __restrict__ vt,   // [16][128][2048]
    const float* __restrict__ bias_tab, // [16][2048], log2 units
    u16* __restrict__ Pacc,       // [1024 slots][64][128] bf16
    float* __restrict__ Pm,       // [1024 slots][64]
    float* __restrict__ Pl) {     // [1024 slots][64]
    __shared__ char ldsK[2][32 * 256];   // 8 KB each
    __shared__ char ldsV[2][128 * 64];   // 8 KB each

    const int bid = blockIdx.x;
    const int xcd = bid & 7, idx = bid >> 3;
    const int work = xcd * 128 + idx;              // 2 heads per XCD
    const int h = work >> 6, rem = work & 63;
    const int qt = 15 - (rem >> 2), chunk = rem & 3;   // qt descending: big first
    const int qbase = qt * 64;
    const int tid = threadIdx.x, lane = tid & 63, wid = tid >> 6;
    const int lhi = lane >> 4, llo = lane & 15;
    const int slot = (h * 16 + qt) * 4 + chunk;

    const u16* kg = kb + (size_t)h * 2048 * 128;
    const u16* vg = vt + (size_t)h * 128 * 2048;
    const float* bt = bias_tab + h * 2048;

    // Q as B-operand fragment: col (n) = llo = q, k-chunks per lhi
    bf16x8 qf[4];
    {
        const u16* qrow = qb + ((size_t)h * 1024 + qbase + wid * 16 + llo) * 128;
#pragma unroll
        for (int c = 0; c < 4; ++c)
            qf[c] = *(const bf16x8*)(qrow + c * 32 + lhi * 8);
    }

    f32x4 acc[8];
#pragma unroll
    for (int d = 0; d < 8; ++d) acc[d] = f32x4{0.f, 0.f, 0.f, 0.f};
    float mrow = -3e38f;      // running max for q = llo (uniform across lhi groups)
    float lrow = 0.f;         // per-lane partial sum (reduced across lhi at end)

    const int ntiles = 34 + 2 * qt;                // 32-key tiles
    const int qpos = 1024 + qbase + wid * 16 + llo;

    auto stage = [&](int b, int st) {
        int sbase = st * 32;
#pragma unroll
        for (int it = 0; it < 2; ++it) {           // K: 32 rows x 16 chunks of 16B
            int ci = it * 256 + tid;
            int r = ci >> 4, c = ci & 15;
            int sc = c ^ (r & 7);
            GLD_LDS16(kg + (size_t)(sbase + r) * 128 + sc * 8,
                      &ldsK[b][0] + (it * 256 + wid * 64) * 16);
        }
#pragma unroll
        for (int it = 0; it < 2; ++it) {           // V: 128 rows x 4 chunks of 16B
            int ci = it * 256 + tid;
            int r = ci >> 2, c = ci & 3;
            int sc = c ^ ((r >> 1) & 3);
            GLD_LDS16(vg + (size_t)r * 2048 + sbase + sc * 8,
                      &ldsV[b][0] + (it * 256 + wid * 64) * 16);
        }
    };

    // in-register P permutation: p0..p3 hold keys {lhi*4+0,1},{2,3},{16+lhi*4+0,1},{2,3}
    // for q=llo -> A-fragment (row=q=llo, keys lhi*8..lhi*8+7) via xor16/32/48 exchanges
    auto permP = [&](u32 p0, u32 p1, u32 p2, u32 p3) -> bf16x8 {
        u32 r16a = (u32)__shfl_xor((int)(lhi == 1 ? p0 : p2), 16);
        u32 r16b = (u32)__shfl_xor((int)(lhi == 1 ? p1 : p3), 16);
        u32 r32a = (u32)__shfl_xor((int)(lhi == 3 ? p0 : p2), 32);
        u32 r32b = (u32)__shfl_xor((int)(lhi == 3 ? p1 : p3), 32);
        u32 r48a = (u32)__shfl_xor((int)(lhi == 2 ? p0 : p2), 48);
        u32 r48b = (u32)__shfl_xor((int)(lhi == 2 ? p1 : p3), 48);
        union { u32 w[4]; bf16x8 v; } u;
        u.w[0] = lhi == 0 ? p0 : lhi == 1 ? r48a : lhi == 2 ? r32a : r16a;
        u.w[1] = lhi == 0 ? p1 : lhi == 1 ? r48b : lhi == 2 ? r32b : r16b;
        u.w[2] = lhi == 0 ? r16a : lhi == 1 ? r32a : lhi == 2 ? r48a : p2;
        u.w[3] = lhi == 0 ? r16b : lhi == 1 ? r32b : lhi == 2 ? r48b : p3;
        return u.v;
    };

    // descending tile order: near-diagonal (high-bias) first -> few rescales
    const int st0 = chunk + 4 * ((ntiles - 1 - chunk) >> 2);
    stage(0, st0);
    __syncthreads();
    int cur = 0;
    for (int st = st0; st >= chunk; st -= 4) {
        if (st >= chunk + 4) stage(cur ^ 1, st - 4);
        const int sbase = st * 32;
        const char* lK = &ldsK[cur][0];
        const char* lV = &ldsV[cur][0];

        // bias windows: dist = qpos - (sbase + sub*16 + lhi*4 + j)
        const int D0 = qpos - sbase - lhi * 4;
        f32x4u wB = *(const f32x4u*)(bt + (D0 - 3 < 0 ? 0 : D0 - 3));
        f32x4u wC = *(const f32x4u*)(bt + (D0 - 19 < 0 ? 0 : D0 - 19));

        // swapped QK^T: A = K rows (keys), B = Q (q = llo)
        f32x4 sc4[2];
        __builtin_amdgcn_s_setprio(1);
#pragma unroll
        for (int sub = 0; sub < 2; ++sub) {
            f32x4 s4 = f32x4{0.f, 0.f, 0.f, 0.f};
            int key = sub * 16 + llo;
#pragma unroll
            for (int c2 = 0; c2 < 4; ++c2) {
                int cl = c2 * 4 + lhi;
                bf16x8 kf = *(const bf16x8*)(lK + key * 256 + ((cl ^ (key & 7)) << 4));
                s4 = mfma16(kf, qf[c2], s4);
            }
            sc4[sub] = s4;
        }
        __builtin_amdgcn_s_setprio(0);

        // bias + causal mask (wave-uniform branch; only diagonal tiles mask)
        if (sbase + 31 <= 1024 + qbase + wid * 16) {
#pragma unroll
            for (int j = 0; j < 4; ++j) {
                sc4[0][j] += wB[3 - j];
                sc4[1][j] += wC[3 - j];
            }
        } else {
#pragma unroll
            for (int sub = 0; sub < 2; ++sub)
#pragma unroll
                for (int j = 0; j < 4; ++j) {
                    int key = sbase + sub * 16 + lhi * 4 + j;
                    int dist = qpos - key;
                    float bv = bt[dist < 0 ? 0 : dist];
                    sc4[sub][j] = (dist < 0) ? -3e38f : sc4[sub][j] + bv;
                }
        }

        // defer-max (base-2): lane-local max over 8 keys; rescale past threshold only
        float tmax = fmaxf(fmaxf(fmaxf(sc4[0][0], sc4[0][1]), fmaxf(sc4[0][2], sc4[0][3])),
                           fmaxf(fmaxf(sc4[1][0], sc4[1][1]), fmaxf(sc4[1][2], sc4[1][3])));
        int ok = (tmax <= mrow + 8.0f) ? 1 : 0;
        if (!__all(ok)) {
            float t = tmax;
            t = fmaxf(t, __shfl_xor(t, 16));
            t = fmaxf(t, __shfl_xor(t, 32));
            float mnew = fmaxf(mrow, t);
            float fs = exp2f(mrow - mnew);
            mrow = mnew;
            lrow *= fs;
            float fsj[4];
#pragma unroll
            for (int j = 0; j < 4; ++j)
                fsj[j] = __shfl(fs, lhi * 4 + j);   // acc rows: q = lhi*4+j
#pragma unroll
            for (int d = 0; d < 8; ++d)
#pragma unroll
                for (int j = 0; j < 4; ++j) acc[d][j] *= fsj[j];
        }

        // P = 2^(s-m) in-register; pack to bf16; lrow sums the PACKED values
        float p[8];
#pragma unroll
        for (int sub = 0; sub < 2; ++sub)
#pragma unroll
            for (int j = 0; j < 4; ++j)
                p[sub * 4 + j] = exp2f(sc4[sub][j] - mrow);
        u32 pk0 = cvt_pk_bf16(p[0], p[1]), pk1 = cvt_pk_bf16(p[2], p[3]);
        u32 pk2 = cvt_pk_bf16(p[4], p[5]), pk3 = cvt_pk_bf16(p[6], p[7]);
        lrow += bf2f((u16)(pk0 & 0xFFFF)) + bf2f((u16)(pk0 >> 16))
              + bf2f((u16)(pk1 & 0xFFFF)) + bf2f((u16)(pk1 >> 16))
              + bf2f((u16)(pk2 & 0xFFFF)) + bf2f((u16)(pk2 >> 16))
              + bf2f((u16)(pk3 & 0xFFFF)) + bf2f((u16)(pk3 >> 16));
        bf16x8 pa = permP(pk0, pk1, pk2, pk3);

        // PV: A = P (rows = q), B = V^T rows = d
        __builtin_amdgcn_s_setprio(1);
#pragma unroll
        for (int db = 0; db < 8; ++db) {
            int dr = db * 16 + llo;
            int cl = lhi ^ ((dr >> 1) & 3);
            bf16x8 vf = *(const bf16x8*)(lV + dr * 64 + cl * 16);
            acc[db] = mfma16(pa, vf, acc[db]);
        }
        __builtin_amdgcn_s_setprio(0);
        __syncthreads();
        cur ^= 1;
    }

    // final sum-reduce of per-lane lrow partials across lhi groups
    {
        float t = lrow;
        t += __shfl_xor(t, 16);
        t += __shfl_xor(t, 32);
        lrow = t;
    }

    if (lhi == 0) {
        int r = wid * 16 + llo;
        Pm[(size_t)slot * 64 + r] = mrow;
        Pl[(size_t)slot * 64 + r] = lrow;
    }
#pragma unroll
    for (int db = 0; db < 8; ++db)
#pragma unroll
        for (int j = 0; j < 4; ++j) {
            int r = wid * 16 + lhi * 4 + j;        // q row
            Pacc[(size_t)slot * 8192 + r * 128 + db * 16 + llo] = f2bf(acc[db][j]);
        }
}

// ---------------- K4b: merge 4-way split-S partials (1024 blocks, 4/CU) ----------------
__global__ __launch_bounds__(256) void k_merge(
    const u16* __restrict__ Pacc, const float* __restrict__ Pm,
    const float* __restrict__ Pl, u16* __restrict__ yb) {
    const int b = blockIdx.x;
    const int h = b >> 6, qt = (b >> 2) & 15, quarter = b & 3;
    const int slot0 = (h * 16 + qt) * 4;
    const int tid = threadIdx.x;
    const int r = tid >> 2, dd = (tid & 3) * 8 + quarter * 32;

    float m[4], l[4];
#pragma unroll
    for (int c = 0; c < 4; ++c) {
        m[c] = Pm[(size_t)(slot0 + c) * 64 + r];
        l[c] = Pl[(size_t)(slot0 + c) * 64 + r];
    }
    float M = fmaxf(fmaxf(m[0], m[1]), fmaxf(m[2], m[3]));
    float w[4], L = 0.f;
#pragma unroll
    for (int c = 0; c < 4; ++c) {
        w[c] = exp2f(m[c] - M);
        L += w[c] * l[c];
    }
    float inv = 1.0f / L;

    float y[8];
#pragma unroll
    for (int i = 0; i < 8; ++i) y[i] = 0.f;
#pragma unroll
    for (int c = 0; c < 4; ++c) {
        const uint4* pa = (const uint4*)(Pacc + (size_t)(slot0 + c) * 8192 + r * 128 + dd);
        float wc = w[c];
        uint4 v = *pa;
        u32 a[4] = {v.x, v.y, v.z, v.w};
#pragma unroll
        for (int p = 0; p < 4; ++p) {
            y[p * 2]     += wc * bf2f((u16)(a[p] & 0xFFFF));
            y[p * 2 + 1] += wc * bf2f((u16)(a[p] >> 16));
        }
    }
    int trow = qt * 64 + r;
    uint4 outv;
    u32* ow = (u32*)&outv;
#pragma unroll
    for (int k = 0; k < 4; ++k)
        ow[k] = (u32)f2bf(y[2 * k] * inv) | ((u32)f2bf(y[2 * k + 1] * inv) << 16);
    *(uint4*)(yb + (size_t)trow * 2048 + h * 128 + dd) = outv;
}

// ---------------- launch ----------------
extern "C" void kernel_launch(void* const* d_in, const int* in_sizes, int n_in,
                              void* d_out, int out_size, void* d_ws, size_t ws_size,
                              hipStream_t stream) {
    (void)in_sizes; (void)n_in; (void)out_size;
    const float* x         = (const float*)d_in[0];
    const float* cached_k  = (const float*)d_in[1];
    const float* cached_v  = (const float*)d_in[2];
    const float* W_attn    = (const float*)d_in[3];
    const float* b_attn    = (const float*)d_in[4];
    const float* W_proj    = (const float*)d_in[5];
    const float* b_proj    = (const float*)d_in[6];
    const float* decay_raw = (const float*)d_in[7];

    float* out_y = (float*)d_out;                  // 1024*2048
    float* out_k = out_y + 2097152;                // 16*2048*128
    float* out_v = out_y + 6291456;                // 16*2048*128

    char* ws = (char*)d_ws;
    if (ws_size < 63569920) return;
    // phase-1 regions
    u16*   WaT  = (u16*)(ws);                      // 6144x2048 bf16   25165824 B
    u16*   WpT  = (u16*)(ws + 25165824);           // 2048x2048 bf16    8388608 B (persists)
    u16*   Xb   = (u16*)(ws + 33554432);           // 1024x2048 bf16    4194304 B
    u16*   QKVb = (u16*)(ws + 37748736);           // 1024x6144 bf16   12582912 B
    float* BT   = (float*)(ws + 62914560);         // 16x2048 f32 (persists)
    float* CT   = (float*)(ws + 63045632);         // 1024x64 f32
    float* ST   = (float*)(ws + 63307776);         // 1024x64 f32
    // phase-2 aliases (dead regions reused)
    u16*   Qb   = (u16*)(ws);                      // in WaT   4194304 B
    u16*   Kb   = (u16*)(ws + 4194304);            // in WaT   8388608 B
    u16*   Vt   = (u16*)(ws + 12582912);           // in WaT   8388608 B
    u16*   Yb   = (u16*)(ws + 20971520);           // in WaT   4194304 B
    float* Pm   = (float*)(ws + 33554432);         // in Xb     262144 B
    float* Pl   = (float*)(ws + 33816576);         // in Xb     262144 B
    u16*   Pacc = (u16*)(ws + 37748736);           // over QKVb 16777216 B

    k_prep<<<6400, 256, 0, stream>>>(W_attn, W_proj, x, decay_raw, WaT, WpT, Xb, BT, CT, ST);
    k_gemm_bt<128, 64, 2, 2, u16><<<768, 256, 0, stream>>>(Xb, WaT, b_attn, QKVb, 1024, 6144, 2048);
    k_mid<<<4096, 256, 0, stream>>>(QKVb, CT, ST, cached_k, cached_v, Qb, Kb, out_k, out_v, Vt);
    k_attn<<<1024, 256, 0, stream>>>(Qb, Kb, Vt, BT, Pacc, Pm, Pl);
    k_merge<<<1024, 256, 0, stream>>>(Pacc, Pm, Pl, Yb);
    k_gemm_bt<64, 32, 2, 2, float><<<1024, 256, 0, stream>>>(Yb, WpT, b_proj, out_y, 1024, 2048, 2048);
}

// Round 19
// 131.466 us; speedup vs baseline: 1.2703x; 1.0024x over previous
//
#include <hip/hip_runtime.h>
#include <hip/hip_bf16.h>

typedef unsigned short u16;
typedef unsigned int u32;
typedef __attribute__((ext_vector_type(4))) float f32x4;
typedef float f32x4u __attribute__((ext_vector_type(4), aligned(4)));
typedef __attribute__((ext_vector_type(8))) short bf16x8;

__device__ __forceinline__ u16 f2bf(float f) {
    union { float f; u32 u; } v; v.f = f;
    return (u16)((v.u + 0x7FFFu + ((v.u >> 16) & 1u)) >> 16);
}
__device__ __forceinline__ float bf2f(u16 b) {
    union { u32 u; float f; } v; v.u = ((u32)b) << 16;
    return v.f;
}
__device__ __forceinline__ void st_out(float* p, float v) { *p = v; }
__device__ __forceinline__ void st_out(u16* p, float v) { *p = f2bf(v); }

__device__ __forceinline__ f32x4 mfma16(bf16x8 a, bf16x8 b, f32x4 c) {
    return __builtin_amdgcn_mfma_f32_16x16x32_bf16(a, b, c, 0, 0, 0);
}
__device__ __forceinline__ u32 cvt_pk_bf16(float lo, float hi) {
    u32 r;
    asm("v_cvt_pk_bf16_f32 %0, %1, %2" : "=v"(r) : "v"(lo), "v"(hi));
    return r;
}

#define GLD_LDS16(g, l) __builtin_amdgcn_global_load_lds( \
    (const __attribute__((address_space(1))) void*)(g),   \
    (__attribute__((address_space(3))) void*)(l), 16, 0, 0)

#define LOG2E 1.4426950408889634f
#define QSCALE 0.12751743f   /* (1/sqrt(128)) * log2e */

// ---------------- K_prep: tables + W transposes + x convert (fused) ----------------
__global__ __launch_bounds__(256) void k_prep(
    const float* __restrict__ W_attn, const float* __restrict__ W_proj,
    const float* __restrict__ x, const float* __restrict__ decay_raw,
    u16* __restrict__ WaT, u16* __restrict__ WpT, u16* __restrict__ Xb,
    float* __restrict__ bias_tab, float* __restrict__ cosT, float* __restrict__ sinT) {
    __shared__ float tile[64][65];
    const int b = blockIdx.x, tid = threadIdx.x;
    if (b < 4096) {
        // transpose f32 (R x Cc) -> bf16 (Cc x R)
        const float* src; u16* dst; int R, Cc, bx, by;
        if (b < 3072) { src = W_attn; dst = WaT; R = 2048; Cc = 6144; bx = b % 96; by = b / 96; }
        else          { src = W_proj; dst = WpT; R = 2048; Cc = 2048; bx = (b - 3072) & 31; by = (b - 3072) >> 5; }
        int c0 = bx * 64, r0 = by * 64;
        // vectorized float4 reads: 16 lanes cover one 256B tile row
#pragma unroll
        for (int it = 0; it < 4; ++it) {
            int idx = it * 256 + tid;              // 0..1023
            int r = idx >> 4, c4 = (idx & 15) * 4;
            float4 v = *(const float4*)(src + (size_t)(r0 + r) * Cc + c0 + c4);
            tile[r][c4]     = v.x; tile[r][c4 + 1] = v.y;
            tile[r][c4 + 2] = v.z; tile[r][c4 + 3] = v.w;
        }
        __syncthreads();
        // vectorized write: each thread packs 4 consecutive rr into uint2 (8B/lane)
#pragma unroll
        for (int it = 0; it < 4; ++it) {
            int idx = it * 256 + tid;              // 0..1023
            int cc = idx >> 4;                     // 0..63
            int rr0 = (idx & 15) * 4;
            u32 lo = (u32)f2bf(tile[rr0][cc])     | ((u32)f2bf(tile[rr0 + 1][cc]) << 16);
            u32 hi = (u32)f2bf(tile[rr0 + 2][cc]) | ((u32)f2bf(tile[rr0 + 3][cc]) << 16);
            uint2 p; p.x = lo; p.y = hi;
            *(uint2*)(dst + (size_t)(c0 + cc) * R + r0 + rr0) = p;
        }
    } else if (b < 6144) {
        int i = (b - 4096) * 256 + tid;          // 524288 float4s
        float4 v = ((const float4*)x)[i];
        u32 p0 = (u32)f2bf(v.x) | ((u32)f2bf(v.y) << 16);
        u32 p1 = (u32)f2bf(v.z) | ((u32)f2bf(v.w) << 16);
        uint2 p; p.x = p0; p.y = p1;
        *(uint2*)(Xb + (size_t)i * 4) = p;
    } else {
        int i = (b - 6144) * 256 + tid;
        if (i < 16 * 2048) {
            int h = i >> 11, dist = i & 2047;
            float dec = log1pf(expf(decay_raw[h]));
            bias_tab[i] = -log1pf(dec * log1pf((float)dist)) * LOG2E;   // log2 units
        }
        if (i < 1024 * 64) {
            int t = i >> 6, j = i & 63;
            float inv = expf(-logf(10000.0f) * (float)j / 64.0f);
            float ang = (float)(1024 + t) * inv;
            cosT[i] = cosf(ang);
            sinT[i] = sinf(ang);
        }
    }
}

// ---------------- GEMM: A (MxK) bf16 row-major, Bt (NxK) bf16 row-major ----------------
// Double-buffered 2-phase, ONE __syncthreads per tile (R4/R8/R14-proven stable).
// 1D grid with XCD-chunked swizzle: each XCD gets a contiguous N-slice (all M)
// so its B panel is L2-resident. Requires gridDim.x % 8 == 0.
template<int BM, int BN, int WRG, int WCG, typename OT>
__global__ __launch_bounds__(256) void k_gemm_bt(
    const u16* __restrict__ A, const u16* __restrict__ Bt,
    const float* __restrict__ bias, OT* __restrict__ C,
    int M, int N, int K) {
    constexpr int BK = 64;
    constexpr int WM = BM / WRG;
    constexpr int WN = BN / WCG;
    constexpr int MR = WM / 16;
    constexpr int NR = WN / 16;
    constexpr int LDSZ = (BM + BN) * BK * 2;
    __shared__ char lds[2][LDSZ];

    const int tid = threadIdx.x;
    const int lane = tid & 63, wid = tid >> 6;
    const int wr = wid / WCG, wc = wid % WCG;
    const int lhi = lane >> 4, llo = lane & 15;

    // XCD-chunked swizzle: xcd = bid % 8 gets work ids [xcd*per, (xcd+1)*per)
    const int per = gridDim.x >> 3;
    const int w = (blockIdx.x & 7) * per + (blockIdx.x >> 3);
    const int mblocks = M / BM;
    const int m0 = (w % mblocks) * BM, n0 = (w / mblocks) * BN;   // n-major chunks

    f32x4 acc[MR][NR];
#pragma unroll
    for (int m = 0; m < MR; ++m)
#pragma unroll
        for (int n = 0; n < NR; ++n)
            acc[m][n] = f32x4{0.f, 0.f, 0.f, 0.f};

    auto stage = [&](int buf, int k0) {
        char* ldsA = &lds[buf][0];
        char* ldsB = &lds[buf][0] + BM * BK * 2;
#pragma unroll
        for (int it = 0; it < (BM * 8) / 256; ++it) {
            int ci = it * 256 + wid * 64 + lane;
            int r = ci >> 3, c = ci & 7;
            int sc = c ^ (r & 7);
            GLD_LDS16(A + (size_t)(m0 + r) * K + k0 + sc * 8,
                      ldsA + (it * 256 + wid * 64) * 16);
        }
#pragma unroll
        for (int it = 0; it < (BN * 8) / 256; ++it) {
            int ci = it * 256 + wid * 64 + lane;
            int r = ci >> 3, c = ci & 7;
            int sc = c ^ (r & 7);
            GLD_LDS16(Bt + (size_t)(n0 + r) * K + k0 + sc * 8,
                      ldsB + (it * 256 + wid * 64) * 16);
        }
    };

    stage(0, 0);
    __syncthreads();
    int cur = 0;
    for (int k0 = 0; k0 < K; k0 += BK) {
        if (k0 + BK < K) stage(cur ^ 1, k0 + BK);
        const char* ldsA = &lds[cur][0];
        const char* ldsB = &lds[cur][0] + BM * BK * 2;
#pragma unroll
        for (int kk = 0; kk < BK; kk += 32) {
            bf16x8 af[MR], bfr[NR];
            const int clb = (kk >> 3) + lhi;
#pragma unroll
            for (int m = 0; m < MR; ++m) {
                int row = wr * WM + m * 16 + llo;
                af[m] = *(const bf16x8*)(ldsA + row * 128 + ((clb ^ (row & 7)) << 4));
            }
#pragma unroll
            for (int n = 0; n < NR; ++n) {
                int row = wc * WN + n * 16 + llo;
                bfr[n] = *(const bf16x8*)(ldsB + row * 128 + ((clb ^ (row & 7)) << 4));
            }
#pragma unroll
            for (int m = 0; m < MR; ++m)
#pragma unroll
                for (int n = 0; n < NR; ++n)
                    acc[m][n] = mfma16(af[m], bfr[n], acc[m][n]);
        }
        __syncthreads();
        cur ^= 1;
    }
#pragma unroll
    for (int m = 0; m < MR; ++m) {
        int row = m0 + wr * WM + m * 16 + lhi * 4;
#pragma unroll
        for (int n = 0; n < NR; ++n) {
            int col = n0 + wc * WN + n * 16 + llo;
            float bv = bias[col];
#pragma unroll
            for (int j = 0; j < 4; ++j)
                st_out(&C[(size_t)(row + j) * N + col], acc[m][n][j] + bv);
        }
    }
}

// ---------------- K_mid: RoPE q/k + cached K copy + V assemble (fused, vectorized) ----------------
__global__ __launch_bounds__(256) void k_mid(
    const u16* __restrict__ qkv,
    const float* __restrict__ cosT, const float* __restrict__ sinT,
    const float* __restrict__ cached_k, const float* __restrict__ cached_v,
    u16* __restrict__ qb, u16* __restrict__ kb,
    float* __restrict__ out_k, float* __restrict__ out_v, u16* __restrict__ vt) {
    __shared__ u16 tile[64][65];
    const int b = blockIdx.x;
    if (b < 1024) {
        // RoPE: 4 consecutive j per thread (vectorized loads/stores)
        int e = b * 256 + threadIdx.x;             // 0..262143
        int j0 = (e & 15) * 4;
        int t = (e >> 4) & 1023;
        int h = e >> 14;
        const u16* row = qkv + (size_t)t * 6144;
        uint2 q1v = *(const uint2*)(row + h * 128 + j0);
        uint2 q2v = *(const uint2*)(row + h * 128 + j0 + 64);
        uint2 k1v = *(const uint2*)(row + 2048 + h * 128 + j0);
        uint2 k2v = *(const uint2*)(row + 2048 + h * 128 + j0 + 64);
        float4 cv4 = *(const float4*)(cosT + t * 64 + j0);
        float4 sv4 = *(const float4*)(sinT + t * 64 + j0);
        float q1[4] = { bf2f((u16)(q1v.x & 0xFFFF)), bf2f((u16)(q1v.x >> 16)),
                        bf2f((u16)(q1v.y & 0xFFFF)), bf2f((u16)(q1v.y >> 16)) };
        float q2[4] = { bf2f((u16)(q2v.x & 0xFFFF)), bf2f((u16)(q2v.x >> 16)),
                        bf2f((u16)(q2v.y & 0xFFFF)), bf2f((u16)(q2v.y >> 16)) };
        float k1[4] = { bf2f((u16)(k1v.x & 0xFFFF)), bf2f((u16)(k1v.x >> 16)),
                        bf2f((u16)(k1v.y & 0xFFFF)), bf2f((u16)(k1v.y >> 16)) };
        float k2[4] = { bf2f((u16)(k2v.x & 0xFFFF)), bf2f((u16)(k2v.x >> 16)),
                        bf2f((u16)(k2v.y & 0xFFFF)), bf2f((u16)(k2v.y >> 16)) };
        float cv[4] = { cv4.x, cv4.y, cv4.z, cv4.w };
        float sv[4] = { sv4.x, sv4.y, sv4.z, sv4.w };
        float qo1[4], qo2[4], ko1[4], ko2[4];
#pragma unroll
        for (int u = 0; u < 4; ++u) {
            qo1[u] = q1[u] * cv[u] - q2[u] * sv[u];
            qo2[u] = q1[u] * sv[u] + q2[u] * cv[u];
            ko1[u] = k1[u] * cv[u] - k2[u] * sv[u];
            ko2[u] = k1[u] * sv[u] + k2[u] * cv[u];
        }
        size_t qoff = ((size_t)h * 1024 + t) * 128 + j0;
        uint2 pq1, pq2, pk1o, pk2o;
        pq1.x = (u32)f2bf(qo1[0] * QSCALE) | ((u32)f2bf(qo1[1] * QSCALE) << 16);
        pq1.y = (u32)f2bf(qo1[2] * QSCALE) | ((u32)f2bf(qo1[3] * QSCALE) << 16);
        pq2.x = (u32)f2bf(qo2[0] * QSCALE) | ((u32)f2bf(qo2[1] * QSCALE) << 16);
        pq2.y = (u32)f2bf(qo2[2] * QSCALE) | ((u32)f2bf(qo2[3] * QSCALE) << 16);
        *(uint2*)(qb + qoff) = pq1;
        *(uint2*)(qb + qoff + 64) = pq2;
        size_t koff = ((size_t)h * 2048 + 1024 + t) * 128 + j0;
        pk1o.x = (u32)f2bf(ko1[0]) | ((u32)f2bf(ko1[1]) << 16);
        pk1o.y = (u32)f2bf(ko1[2]) | ((u32)f2bf(ko1[3]) << 16);
        pk2o.x = (u32)f2bf(ko2[0]) | ((u32)f2bf(ko2[1]) << 16);
        pk2o.y = (u32)f2bf(ko2[2]) | ((u32)f2bf(ko2[3]) << 16);
        *(uint2*)(kb + koff) = pk1o;
        *(uint2*)(kb + koff + 64) = pk2o;
        float4 o1; o1.x = ko1[0]; o1.y = ko1[1]; o1.z = ko1[2]; o1.w = ko1[3];
        float4 o2; o2.x = ko2[0]; o2.y = ko2[1]; o2.z = ko2[2]; o2.w = ko2[3];
        *(float4*)(out_k + koff) = o1;
        *(float4*)(out_k + koff + 64) = o2;
    } else if (b < 3072) {
        // cached K copy: 4 consecutive d per thread
        int e = (b - 1024) * 256 + threadIdx.x;    // 0..524287
        size_t i0 = (size_t)e * 4;
        int d0 = (int)(i0 & 127);
        int s = (int)((i0 >> 7) & 1023);
        int h = (int)(i0 >> 17);
        float4 v = *(const float4*)(cached_k + i0);
        size_t off = ((size_t)h * 2048 + s) * 128 + d0;
        *(float4*)(out_k + off) = v;
        uint2 p;
        p.x = (u32)f2bf(v.x) | ((u32)f2bf(v.y) << 16);
        p.y = (u32)f2bf(v.z) | ((u32)f2bf(v.w) << 16);
        *(uint2*)(kb + off) = p;
    } else {
        // V assemble: out_v f32 + per-head transposed bf16
        int idx2 = b - 3072;                       // 1024 blocks
        int s0 = (idx2 & 31) * 64, d0 = ((idx2 >> 5) & 1) * 64, h = idx2 >> 6;
        int tid = threadIdx.x;
#pragma unroll
        for (int it = 0; it < 16; ++it) {
            int idx = it * 256 + tid;
            int r = idx >> 6, c = idx & 63;
            int s = s0 + r, d = d0 + c;
            u16 v = (s < 1024)
                ? f2bf(cached_v[((size_t)h * 1024 + s) * 128 + d])
                : qkv[(size_t)(s - 1024) * 6144 + 4096 + h * 128 + d];
            tile[r][c] = v;
            out_v[((size_t)h * 2048 + s) * 128 + d] = bf2f(v);
        }
        __syncthreads();
        // vectorized transpose write: 4 consecutive ss per thread -> uint2
#pragma unroll
        for (int it = 0; it < 4; ++it) {
            int idx = it * 256 + tid;              // 0..1023
            int dd = idx >> 4;                     // 0..63
            int ss0 = (idx & 15) * 4;
            u32 lo = (u32)tile[ss0][dd]     | ((u32)tile[ss0 + 1][dd] << 16);
            u32 hi = (u32)tile[ss0 + 2][dd] | ((u32)tile[ss0 + 3][dd] << 16);
            uint2 p; p.x = lo; p.y = hi;
            *(uint2*)(vt + ((size_t)h * 128 + d0 + dd) * 2048 + s0 + ss0) = p;
        }
    }
}

// ---------------- K4: flash attention v5b (R14/R17/R18-proven LDS-V __syncthreads version) ----------------
// 4 waves x 16 q-rows, 4-way split-S (grid 1024 = 4 blocks/CU), qt-descending,
// KVBLK=32 dbuf, swapped QK^T, lane-local softmax, in-register P (cvt_pk +
// xor16/32/48 permute, no ldsP), lrow summed from the SAME bf16 P used in PV.
__global__ __launch_bounds__(256, 4) void k_attn(
    const u16* __restrict__ qb,   // [16][1024][128], pre-scaled
    const u16* __restrict__ kb,   // [16][2048][128]
    const u16* __restrict__ vt,   // [16][128][2048]
    const float* __restrict__ bias_tab, // [16][2048], log2 units
    u16* __restrict__ Pacc,       // [1024 slots][64][128] bf16
    float* __restrict__ Pm,       // [1024 slots][64]
    float* __restrict__ Pl) {     // [1024 slots][64]
    __shared__ char ldsK[2][32 * 256];   // 8 KB each
    __shared__ char ldsV[2][128 * 64];   // 8 KB each

    const int bid = blockIdx.x;
    const int xcd = bid & 7, idx = bid >> 3;
    const int work = xcd * 128 + idx;              // 2 heads per XCD
    const int h = work >> 6, rem = work & 63;
    const int qt = 15 - (rem >> 2), chunk = rem & 3;   // qt descending: big first
    const int qbase = qt * 64;
    const int tid = threadIdx.x, lane = tid & 63, wid = tid >> 6;
    const int lhi = lane >> 4, llo = lane & 15;
    const int slot = (h * 16 + qt) * 4 + chunk;

    const u16* kg = kb + (size_t)h * 2048 * 128;
    const u16* vg = vt + (size_t)h * 128 * 2048;
    const float* bt = bias_tab + h * 2048;

    // Q as B-operand fragment: col (n) = llo = q, k-chunks per lhi
    bf16x8 qf[4];
    {
        const u16* qrow = qb + ((size_t)h * 1024 + qbase + wid * 16 + llo) * 128;
#pragma unroll
        for (int c = 0; c < 4; ++c)
            qf[c] = *(const bf16x8*)(qrow + c * 32 + lhi * 8);
    }

    f32x4 acc[8];
#pragma unroll
    for (int d = 0; d < 8; ++d) acc[d] = f32x4{0.f, 0.f, 0.f, 0.f};
    float mrow = -3e38f;      // running max for q = llo (uniform across lhi groups)
    float lrow = 0.f;         // per-lane partial sum (reduced across lhi at end)

    const int ntiles = 34 + 2 * qt;                // 32-key tiles
    const int qpos = 1024 + qbase + wid * 16 + llo;

    auto stage = [&](int b, int st) {
        int sbase = st * 32;
#pragma unroll
        for (int it = 0; it < 2; ++it) {           // K: 32 rows x 16 chunks of 16B
            int ci = it * 256 + tid;
            int r = ci >> 4, c = ci & 15;
            int sc = c ^ (r & 7);
            GLD_LDS16(kg + (size_t)(sbase + r) * 128 + sc * 8,
                      &ldsK[b][0] + (it * 256 + wid * 64) * 16);
        }
#pragma unroll
        for (int it = 0; it < 2; ++it) {           // V: 128 rows x 4 chunks of 16B
            int ci = it * 256 + tid;
            int r = ci >> 2, c = ci & 3;
            int sc = c ^ ((r >> 1) & 3);
            GLD_LDS16(vg + (size_t)r * 2048 + sbase + sc * 8,
                      &ldsV[b][0] + (it * 256 + wid * 64) * 16);
        }
    };

    // in-register P permutation: p0..p3 hold keys {lhi*4+0,1},{2,3},{16+lhi*4+0,1},{2,3}
    // for q=llo -> A-fragment (row=q=llo, keys lhi*8..lhi*8+7) via xor16/32/48 exchanges
    auto permP = [&](u32 p0, u32 p1, u32 p2, u32 p3) -> bf16x8 {
        u32 r16a = (u32)__shfl_xor((int)(lhi == 1 ? p0 : p2), 16);
        u32 r16b = (u32)__shfl_xor((int)(lhi == 1 ? p1 : p3), 16);
        u32 r32a = (u32)__shfl_xor((int)(lhi == 3 ? p0 : p2), 32);
        u32 r32b = (u32)__shfl_xor((int)(lhi == 3 ? p1 : p3), 32);
        u32 r48a = (u32)__shfl_xor((int)(lhi == 2 ? p0 : p2), 48);
        u32 r48b = (u32)__shfl_xor((int)(lhi == 2 ? p1 : p3), 48);
        union { u32 w[4]; bf16x8 v; } u;
        u.w[0] = lhi == 0 ? p0 : lhi == 1 ? r48a : lhi == 2 ? r32a : r16a;
        u.w[1] = lhi == 0 ? p1 : lhi == 1 ? r48b : lhi == 2 ? r32b : r16b;
        u.w[2] = lhi == 0 ? r16a : lhi == 1 ? r32a : lhi == 2 ? r48a : p2;
        u.w[3] = lhi == 0 ? r16b : lhi == 1 ? r32b : lhi == 2 ? r48b : p3;
        return u.v;
    };

    // descending tile order: near-diagonal (high-bias) first -> few rescales
    const int st0 = chunk + 4 * ((ntiles - 1 - chunk) >> 2);
    stage(0, st0);
    __syncthreads();
    int cur = 0;
    for (int st = st0; st >= chunk; st -= 4) {
        if (st >= chunk + 4) stage(cur ^ 1, st - 4);
        const int sbase = st * 32;
        const char* lK = &ldsK[cur][0];
        const char* lV = &ldsV[cur][0];

        // bias windows: dist = qpos - (sbase + sub*16 + lhi*4 + j)
        const int D0 = qpos - sbase - lhi * 4;
        f32x4u wB = *(const f32x4u*)(bt + (D0 - 3 < 0 ? 0 : D0 - 3));
        f32x4u wC = *(const f32x4u*)(bt + (D0 - 19 < 0 ? 0 : D0 - 19));

        // swapped QK^T: A = K rows (keys), B = Q (q = llo)
        f32x4 sc4[2];
        __builtin_amdgcn_s_setprio(1);
#pragma unroll
        for (int sub = 0; sub < 2; ++sub) {
            f32x4 s4 = f32x4{0.f, 0.f, 0.f, 0.f};
            int key = sub * 16 + llo;
#pragma unroll
            for (int c2 = 0; c2 < 4; ++c2) {
                int cl = c2 * 4 + lhi;
                bf16x8 kf = *(const bf16x8*)(lK + key * 256 + ((cl ^ (key & 7)) << 4));
                s4 = mfma16(kf, qf[c2], s4);
            }
            sc4[sub] = s4;
        }
        __builtin_amdgcn_s_setprio(0);

        // bias + causal mask (wave-uniform branch; only diagonal tiles mask)
        if (sbase + 31 <= 1024 + qbase + wid * 16) {
#pragma unroll
            for (int j = 0; j < 4; ++j) {
                sc4[0][j] += wB[3 - j];
                sc4[1][j] += wC[3 - j];
            }
        } else {
#pragma unroll
            for (int sub = 0; sub < 2; ++sub)
#pragma unroll
                for (int j = 0; j < 4; ++j) {
                    int key = sbase + sub * 16 + lhi * 4 + j;
                    int dist = qpos - key;
                    float bv = bt[dist < 0 ? 0 : dist];
                    sc4[sub][j] = (dist < 0) ? -3e38f : sc4[sub][j] + bv;
                }
        }

        // defer-max (base-2): lane-local max over 8 keys; rescale only past
        // threshold 8*log2e (P bounded by e^8 — R4-R7-proven)
        float tmax = fmaxf(fmaxf(fmaxf(sc4[0][0], sc4[0][1]), fmaxf(sc4[0][2], sc4[0][3])),
                           fmaxf(fmaxf(sc4[1][0], sc4[1][1]), fmaxf(sc4[1][2], sc4[1][3])));
        int ok = (tmax <= mrow + 11.5416f) ? 1 : 0;
        if (!__all(ok)) {
            float t = tmax;
            t = fmaxf(t, __shfl_xor(t, 16));
            t = fmaxf(t, __shfl_xor(t, 32));
            float mnew = fmaxf(mrow, t);
            float fs = exp2f(mrow - mnew);
            mrow = mnew;
            lrow *= fs;
            float fsj[4];
#pragma unroll
            for (int j = 0; j < 4; ++j)
                fsj[j] = __shfl(fs, lhi * 4 + j);   // acc rows: q = lhi*4+j
#pragma unroll
            for (int d = 0; d < 8; ++d)
#pragma unroll
                for (int j = 0; j < 4; ++j) acc[d][j] *= fsj[j];
        }

        // P = 2^(s-m) in-register; pack to bf16; lrow sums the PACKED values
        float p[8];
#pragma unroll
        for (int sub = 0; sub < 2; ++sub)
#pragma unroll
            for (int j = 0; j < 4; ++j)
                p[sub * 4 + j] = exp2f(sc4[sub][j] - mrow);
        u32 pk0 = cvt_pk_bf16(p[0], p[1]), pk1 = cvt_pk_bf16(p[2], p[3]);
        u32 pk2 = cvt_pk_bf16(p[4], p[5]), pk3 = cvt_pk_bf16(p[6], p[7]);
        lrow += bf2f((u16)(pk0 & 0xFFFF)) + bf2f((u16)(pk0 >> 16))
              + bf2f((u16)(pk1 & 0xFFFF)) + bf2f((u16)(pk1 >> 16))
              + bf2f((u16)(pk2 & 0xFFFF)) + bf2f((u16)(pk2 >> 16))
              + bf2f((u16)(pk3 & 0xFFFF)) + bf2f((u16)(pk3 >> 16));
        bf16x8 pa = permP(pk0, pk1, pk2, pk3);

        // PV: A = P (rows = q), B = V^T rows = d
        __builtin_amdgcn_s_setprio(1);
#pragma unroll
        for (int db = 0; db < 8; ++db) {
            int dr = db * 16 + llo;
            int cl = lhi ^ ((dr >> 1) & 3);
            bf16x8 vf = *(const bf16x8*)(lV + dr * 64 + cl * 16);
            acc[db] = mfma16(pa, vf, acc[db]);
        }
        __builtin_amdgcn_s_setprio(0);
        __syncthreads();
        cur ^= 1;
    }

    // final sum-reduce of per-lane lrow partials across lhi groups
    {
        float t = lrow;
        t += __shfl_xor(t, 16);
        t += __shfl_xor(t, 32);
        lrow = t;
    }

    if (lhi == 0) {
        int r = wid * 16 + llo;
        Pm[(size_t)slot * 64 + r] = mrow;
        Pl[(size_t)slot * 64 + r] = lrow;
    }
#pragma unroll
    for (int db = 0; db < 8; ++db)
#pragma unroll
        for (int j = 0; j < 4; ++j) {
            int r = wid * 16 + lhi * 4 + j;        // q row
            Pacc[(size_t)slot * 8192 + r * 128 + db * 16 + llo] = f2bf(acc[db][j]);
        }
}

// ---------------- K4b: merge 4-way split-S partials (1024 blocks, 4/CU) ----------------
__global__ __launch_bounds__(256) void k_merge(
    const u16* __restrict__ Pacc, const float* __restrict__ Pm,
    const float* __restrict__ Pl, u16* __restrict__ yb) {
    const int b = blockIdx.x;
    const int h = b >> 6, qt = (b >> 2) & 15, quarter = b & 3;
    const int slot0 = (h * 16 + qt) * 4;
    const int tid = threadIdx.x;
    const int r = tid >> 2, dd = (tid & 3) * 8 + quarter * 32;

    float m[4], l[4];
#pragma unroll
    for (int c = 0; c < 4; ++c) {
        m[c] = Pm[(size_t)(slot0 + c) * 64 + r];
        l[c] = Pl[(size_t)(slot0 + c) * 64 + r];
    }
    float M = fmaxf(fmaxf(m[0], m[1]), fmaxf(m[2], m[3]));
    float w[4], L = 0.f;
#pragma unroll
    for (int c = 0; c < 4; ++c) {
        w[c] = exp2f(m[c] - M);
        L += w[c] * l[c];
    }
    float inv = 1.0f / L;

    float y[8];
#pragma unroll
    for (int i = 0; i < 8; ++i) y[i] = 0.f;
#pragma unroll
    for (int c = 0; c < 4; ++c) {
        const uint4* pa = (const uint4*)(Pacc + (size_t)(slot0 + c) * 8192 + r * 128 + dd);
        float wc = w[c];
        uint4 v = *pa;
        u32 a[4] = {v.x, v.y, v.z, v.w};
#pragma unroll
        for (int p = 0; p < 4; ++p) {
            y[p * 2]     += wc * bf2f((u16)(a[p] & 0xFFFF));
            y[p * 2 + 1] += wc * bf2f((u16)(a[p] >> 16));
        }
    }
    int trow = qt * 64 + r;
    uint4 outv;
    u32* ow = (u32*)&outv;
#pragma unroll
    for (int k = 0; k < 4; ++k)
        ow[k] = (u32)f2bf(y[2 * k] * inv) | ((u32)f2bf(y[2 * k + 1] * inv) << 16);
    *(uint4*)(yb + (size_t)trow * 2048 + h * 128 + dd) = outv;
}

// ---------------- launch ----------------
extern "C" void kernel_launch(void* const* d_in, const int* in_sizes, int n_in,
                              void* d_out, int out_size, void* d_ws, size_t ws_size,
                              hipStream_t stream) {
    (void)in_sizes; (void)n_in; (void)out_size;
    const float* x         = (const float*)d_in[0];
    const float* cached_k  = (const float*)d_in[1];
    const float* cached_v  = (const float*)d_in[2];
    const float* W_attn    = (const float*)d_in[3];
    const float* b_attn    = (const float*)d_in[4];
    const float* W_proj    = (const float*)d_in[5];
    const float* b_proj    = (const float*)d_in[6];
    const float* decay_raw = (const float*)d_in[7];

    float* out_y = (float*)d_out;                  // 1024*2048
    float* out_k = out_y + 2097152;                // 16*2048*128
    float* out_v = out_y + 6291456;                // 16*2048*128

    char* ws = (char*)d_ws;
    if (ws_size < 63569920) return;
    // phase-1 regions
    u16*   WaT  = (u16*)(ws);                      // 6144x2048 bf16   25165824 B
    u16*   WpT  = (u16*)(ws + 25165824);           // 2048x2048 bf16    8388608 B (persists)
    u16*   Xb   = (u16*)(ws + 33554432);           // 1024x2048 bf16    4194304 B
    u16*   QKVb = (u16*)(ws + 37748736);           // 1024x6144 bf16   12582912 B
    float* BT   = (float*)(ws + 62914560);         // 16x2048 f32 (persists)
    float* CT   = (float*)(ws + 63045632);         // 1024x64 f32
    float* ST   = (float*)(ws + 63307776);         // 1024x64 f32
    // phase-2 aliases (dead regions reused)
    u16*   Qb   = (u16*)(ws);                      // in WaT   4194304 B
    u16*   Kb   = (u16*)(ws + 4194304);            // in WaT   8388608 B
    u16*   Vt   = (u16*)(ws + 12582912);           // in WaT   8388608 B
    u16*   Yb   = (u16*)(ws + 20971520);           // in WaT   4194304 B
    float* Pm   = (float*)(ws + 33554432);         // in Xb     262144 B
    float* Pl   = (float*)(ws + 33816576);         // in Xb     262144 B
    u16*   Pacc = (u16*)(ws + 37748736);           // over QKVb 16777216 B

    k_prep<<<6400, 256, 0, stream>>>(W_attn, W_proj, x, decay_raw, WaT, WpT, Xb, BT, CT, ST);
    k_gemm_bt<128, 64, 2, 2, u16><<<768, 256, 0, stream>>>(Xb, WaT, b_attn, QKVb, 1024, 6144, 2048);
    k_mid<<<4096, 256, 0, stream>>>(QKVb, CT, ST, cached_k, cached_v, Qb, Kb, out_k, out_v, Vt);
    k_attn<<<1024, 256, 0, stream>>>(Qb, Kb, Vt, BT, Pacc, Pm, Pl);
    k_merge<<<1024, 256, 0, stream>>>(Pacc, Pm, Pl, Yb);
    k_gemm_bt<64, 32, 2, 2, float><<<1024, 256, 0, stream>>>(Yb, WpT, b_proj, out_y, 1024, 2048, 2048);
}